// Round 6
// baseline (229.685 us; speedup 1.0000x reference)
//
#include <hip/hip_runtime.h>
#include <math.h>

// Problem constants (fixed by reference)
#define BB 4
#define LL 1024
#define HH 16
#define DH 64
#define DM 1024
#define MM (BB * LL)   // 4096 rows for the projections

typedef short bf16x8 __attribute__((ext_vector_type(8)));
typedef float f32x4  __attribute__((ext_vector_type(4)));
typedef unsigned short u16x4 __attribute__((ext_vector_type(4)));

__device__ __forceinline__ unsigned short f2bf(float x) {
    union { float f; unsigned u; } v; v.f = x;
    unsigned r = v.u + 0x7fff + ((v.u >> 16) & 1);   // round-to-nearest-even
    return (unsigned short)(r >> 16);
}

// async global->LDS, 16B per lane; LDS dest = wave-uniform base + lane*16
__device__ __forceinline__ void gl2lds16(const unsigned short* g, unsigned short* l) {
    __builtin_amdgcn_global_load_lds(
        (const __attribute__((address_space(1))) unsigned int*)g,
        (__attribute__((address_space(3))) unsigned int*)l, 16, 0, 0);
}

// ---------------------------------------------------------------------------
// z in 0..2: f32 -> bf16 flat convert of queries/keys/values (4 elem/thread).
// z == 3  : rope cos/sin table (1024 x 32 each) — only first 32768 items.
// ---------------------------------------------------------------------------
__global__ __launch_bounds__(256) void cvt_bf16_kernel(
    const float* __restrict__ i0, const float* __restrict__ i1, const float* __restrict__ i2,
    unsigned short* __restrict__ o0, unsigned short* __restrict__ o1, unsigned short* __restrict__ o2,
    float* __restrict__ ct, float* __restrict__ st)
{
    int z = blockIdx.z;
    if (z == 3) {
        int idx = blockIdx.x * 256 + threadIdx.x;
        if (idx < LL * 32) {
            int l = idx >> 5, d = idx & 31;
            const float coef = -0.28782313662425583f;   // -ln(10000)/32
            float ang = (float)l * expf((float)d * coef);
            float s, c;
            sincosf(ang, &s, &c);
            ct[idx] = c;
            st[idx] = s;
        }
        return;
    }
    const float* in = (z == 0) ? i0 : (z == 1) ? i1 : i2;
    unsigned short* out = (z == 0) ? o0 : (z == 1) ? o1 : o2;
    int i = (blockIdx.x * 256 + threadIdx.x) * 4;
    float4 f = *(const float4*)(in + i);
    u16x4 r;
    r.x = f2bf(f.x); r.y = f2bf(f.y); r.z = f2bf(f.z); r.w = f2bf(f.w);
    *(u16x4*)(out + i) = r;
}

// ---------------------------------------------------------------------------
// W[K,N] f32 -> Wt[N,K] bf16 transpose (all 4 weights, z picks). 32x32 tiles.
// ---------------------------------------------------------------------------
__global__ __launch_bounds__(256) void transpose_w_kernel(
    const float* __restrict__ w0, const float* __restrict__ w1,
    const float* __restrict__ w2, const float* __restrict__ w3,
    unsigned short* __restrict__ t0, unsigned short* __restrict__ t1,
    unsigned short* __restrict__ t2, unsigned short* __restrict__ t3)
{
    int z = blockIdx.z;
    const float* in = (z == 0) ? w0 : (z == 1) ? w1 : (z == 2) ? w2 : w3;
    unsigned short* out = (z == 0) ? t0 : (z == 1) ? t1 : (z == 2) ? t2 : t3;
    __shared__ float tile[32][33];
    int tx = threadIdx.x & 31, ty = threadIdx.x >> 5;   // 32 x 8
    int c0 = blockIdx.x * 32, r0 = blockIdx.y * 32;
    #pragma unroll
    for (int j = 0; j < 32; j += 8)
        tile[ty + j][tx] = in[(size_t)(r0 + ty + j) * 1024 + c0 + tx];
    __syncthreads();
    #pragma unroll
    for (int j = 0; j < 32; j += 8)
        out[(size_t)(c0 + ty + j) * 1024 + r0 + tx] = f2bf(tile[tx][ty + j]);
}

// ---------------------------------------------------------------------------
// bf16 MFMA GEMM core, double-buffered: C128x128 += A[M,1024].Bt[N,1024]^T.
// BK=64, 2 LDS buffers per operand (64 KB total). Staging for tile kt+1 is
// issued BEFORE computing tile kt; the single per-iter barrier's vmcnt drain
// then lands after 32 MFMAs (latency hidden even at 1-2 blocks/CU).
// LDS unpadded, XOR-swizzled (kb_phys = kb ^ (row&7)).
// ---------------------------------------------------------------------------
__device__ __forceinline__ void stage_tile(
    const unsigned short* __restrict__ A, const unsigned short* __restrict__ Bt,
    unsigned short* As, unsigned short* Bs, int tM, int tN, int kt,
    int wave, int lr, int kbl)
{
    const int k0 = kt * 64;
    #pragma unroll
    for (int it = 0; it < 4; ++it) {
        int rbase = wave * 32 + it * 8;
        int r = rbase + lr;
        gl2lds16(A  + (size_t)(tM + r) * 1024 + k0 + kbl * 8, As + rbase * 64);
        gl2lds16(Bt + (size_t)(tN + r) * 1024 + k0 + kbl * 8, Bs + rbase * 64);
    }
}

__device__ __forceinline__ void gemm128_core(
    const unsigned short* __restrict__ A, const unsigned short* __restrict__ Bt,
    unsigned short* As, unsigned short* Bs,   // each 2 x 128*64
    int tM, int tN, f32x4 (&acc)[4][4])
{
    const int tid  = threadIdx.x;
    const int wave = tid >> 6, lane = tid & 63;
    const int g = lane >> 4, lm = lane & 15;
    const int wm = wave >> 1, wn = wave & 1;
    const int lr = lane >> 3, lk = lane & 7;
    const int kbl = lk ^ lr;                    // swizzled k-block for staging

    stage_tile(A, Bt, As, Bs, tM, tN, 0, wave, lr, kbl);
    __syncthreads();

    for (int kt = 0; kt < 16; ++kt) {
        unsigned short* Ac = As + (kt & 1) * (128 * 64);
        unsigned short* Bc = Bs + (kt & 1) * (128 * 64);
        if (kt + 1 < 16) {
            unsigned short* An = As + ((kt + 1) & 1) * (128 * 64);
            unsigned short* Bn = Bs + ((kt + 1) & 1) * (128 * 64);
            stage_tile(A, Bt, An, Bn, tM, tN, kt + 1, wave, lr, kbl);
        }

        #pragma unroll
        for (int kk = 0; kk < 2; ++kk) {
            bf16x8 a[4], b[4];
            const int sw = ((kk * 4 + g) ^ (lm & 7)) * 8;
            #pragma unroll
            for (int mt = 0; mt < 4; ++mt)
                a[mt] = *(const bf16x8*)&Ac[(wm * 64 + mt * 16 + lm) * 64 + sw];
            #pragma unroll
            for (int nt = 0; nt < 4; ++nt)
                b[nt] = *(const bf16x8*)&Bc[(wn * 64 + nt * 16 + lm) * 64 + sw];
            #pragma unroll
            for (int mt = 0; mt < 4; ++mt)
                #pragma unroll
                for (int nt = 0; nt < 4; ++nt)
                    acc[mt][nt] = __builtin_amdgcn_mfma_f32_16x16x32_bf16(
                        a[mt], b[nt], acc[mt][nt], 0, 0, 0);
        }
        __syncthreads();   // drains this iter's staging AFTER the MFMAs
    }
}

// XCD-aware tile mapping: blocks sharing an A-strip (same tM, 8 tN values)
// get linear ids congruent mod 8 -> same XCD -> A fetched once per strip.
__device__ __forceinline__ void tile_map(int n, int& tM, int& tN) {
    tM = ((n >> 6) * 8 + (n & 7)) * 128;
    tN = ((n >> 3) & 7) * 128;
}

// ---------------------------------------------------------------------------
// QKV projections, fused over blockIdx.z (0=q rope+scale, 1=k rope, 2=v).
// Q scale = 0.125 * log2(e) so attention uses a single exp2.
// Rope cos/sin from precomputed tables. z==2 writes V^T [bh][d][l] (b64).
// ---------------------------------------------------------------------------
__global__ __launch_bounds__(256) void gemm_qkv_kernel(
    const unsigned short* __restrict__ Aq, const unsigned short* __restrict__ Ak,
    const unsigned short* __restrict__ Av,
    const unsigned short* __restrict__ Wqt, const unsigned short* __restrict__ Wkt,
    const unsigned short* __restrict__ Wvt,
    const float* __restrict__ bq, const float* __restrict__ bk, const float* __restrict__ bv,
    const float* __restrict__ ct, const float* __restrict__ st,
    unsigned short* __restrict__ oq, unsigned short* __restrict__ ok,
    unsigned short* __restrict__ vt)
{
    __shared__ __align__(16) unsigned short As[2 * 128 * 64];
    __shared__ __align__(16) unsigned short Bs[2 * 128 * 64];

    const int z = blockIdx.z;
    const unsigned short* A  = (z == 0) ? Aq  : (z == 1) ? Ak  : Av;
    const unsigned short* Bt = (z == 0) ? Wqt : (z == 1) ? Wkt : Wvt;
    const float* bias        = (z == 0) ? bq  : (z == 1) ? bk  : bv;

    int tM, tN;
    tile_map(blockIdx.x, tM, tN);
    f32x4 acc[4][4] = {};
    gemm128_core(A, Bt, As, Bs, tM, tN, acc);

    const int wave = threadIdx.x >> 6, lane = threadIdx.x & 63;
    const int g = lane >> 4, lm = lane & 15;
    const int wm = wave >> 1, wn = wave & 1;

    const int colbase = tN + wn * 64;           // head-aligned (64 cols/wave)
    const int h = colbase >> 6;
    float bvv[4];
    #pragma unroll
    for (int nt = 0; nt < 4; ++nt) bvv[nt] = bias[colbase + nt * 16 + lm];

    if (z == 2) {                               // V: write V^T [bh][d][l], b64
        #pragma unroll
        for (int mt = 0; mt < 4; ++mt) {
            int row0 = tM + wm * 64 + mt * 16 + g * 4;   // 4 consecutive rows
            int b = row0 >> 10, l0 = row0 & 1023;
            #pragma unroll
            for (int nt = 0; nt < 4; ++nt) {
                int dloc = nt * 16 + lm;
                u16x4 p4;
                #pragma unroll
                for (int r = 0; r < 4; ++r)
                    p4[r] = f2bf(acc[mt][nt][r] + bvv[nt]);
                *(u16x4*)(vt + (((size_t)(b * HH + h) * DH + dloc) << 10) + l0) = p4;
            }
        }
    } else {                                    // Q/K: rope from table
        unsigned short* out = (z == 0) ? oq : ok;
        const float sc = (z == 0) ? 0.125f * 1.4426950408889634f : 1.0f;
        #pragma unroll
        for (int mt = 0; mt < 4; ++mt)
            #pragma unroll
            for (int r = 0; r < 4; ++r) {
                int row = tM + wm * 64 + mt * 16 + g * 4 + r;
                int b = row >> 10, l = row & 1023;
                const float* cl = ct + l * 32;
                const float* sl = st + l * 32;
                unsigned short* orow = out + ((size_t)(b * HH + h) * LL + l) * DH;
                #pragma unroll
                for (int nt = 0; nt < 2; ++nt) {
                    float t1 = acc[mt][nt][r]     + bvv[nt];
                    float t2 = acc[mt][nt + 2][r] + bvv[nt + 2];
                    float c = cl[nt * 16 + lm];
                    float s = sl[nt * 16 + lm];
                    orow[nt * 16 + lm]      = f2bf((t1 * c - t2 * s) * sc);
                    orow[nt * 16 + lm + 32] = f2bf((t1 * s + t2 * c) * sc);
                }
            }
    }
}

// ---------------------------------------------------------------------------
// Output projection: f32 C = ctx(bf16) . Wot^T + bo. grid (256).
// ---------------------------------------------------------------------------
__global__ __launch_bounds__(256) void gemm_out_kernel(
    const unsigned short* __restrict__ A, const unsigned short* __restrict__ Bt,
    const float* __restrict__ bias, float* __restrict__ C)
{
    __shared__ __align__(16) unsigned short As[2 * 128 * 64];
    __shared__ __align__(16) unsigned short Bs[2 * 128 * 64];

    int tM, tN;
    tile_map(blockIdx.x, tM, tN);
    f32x4 acc[4][4] = {};
    gemm128_core(A, Bt, As, Bs, tM, tN, acc);

    const int wave = threadIdx.x >> 6, lane = threadIdx.x & 63;
    const int g = lane >> 4, lm = lane & 15;
    const int wm = wave >> 1, wn = wave & 1;

    float bvv[4];
    #pragma unroll
    for (int nt = 0; nt < 4; ++nt) bvv[nt] = bias[tN + wn * 64 + nt * 16 + lm];
    #pragma unroll
    for (int mt = 0; mt < 4; ++mt)
        #pragma unroll
        for (int r = 0; r < 4; ++r) {
            int row = tM + wm * 64 + mt * 16 + g * 4 + r;
            float* crow = C + (size_t)row * DM + tN + wn * 64;
            #pragma unroll
            for (int nt = 0; nt < 4; ++nt)
                crow[nt * 16 + lm] = acc[mt][nt][r] + bvv[nt];
        }
}

// ---------------------------------------------------------------------------
// Flash-style bf16 MFMA attention, S^T formulation, double-buffered staging.
// S^T = K.Q^T; MFMA C-layout gives each lane 4 consecutive j for fixed m=lm:
// P goes to LDS [m][j] with packed ds_write_b64, read back as PV A-frags.
// Row sums: one scalar per lane, reduced with 2 shuffles at the end.
// 1-D grid, bh = n&63 so each head's 16 blocks share an XCD (L2 locality).
// ---------------------------------------------------------------------------
#define PSTR 72

__global__ __launch_bounds__(256) void attn_mfma_kernel(
    const unsigned short* __restrict__ q, const unsigned short* __restrict__ k,
    const unsigned short* __restrict__ vt, unsigned short* __restrict__ ctx)
{
    __shared__ __align__(16) unsigned short Ks[2 * 64 * 64];
    __shared__ __align__(16) unsigned short Vs[2 * 64 * 64];
    __shared__ __align__(16) unsigned short Pb[4][16 * PSTR];

    const int tid  = threadIdx.x;
    const int wave = tid >> 6, lane = tid & 63;
    const int g = lane >> 4, lm = lane & 15;
    const int lr = lane >> 3, lk = lane & 7;
    const int kbl = lk ^ lr;
    const int n = blockIdx.x;
    const int bh = n & 63;              // XCD-swizzle: bh%8 == n%8 == XCD
    const int qbase = (n >> 6) * 64;

    const unsigned short* qg  = q  + (size_t)(bh * LL + qbase) * DH;
    const unsigned short* kg  = k  + (size_t)bh * LL * DH;
    const unsigned short* vtg = vt + (size_t)bh * DH * LL;   // [64 d][1024 l]

    bf16x8 aq[2];
    {
        const unsigned short* qrow = qg + (wave * 16 + lm) * DH;
        aq[0] = *(const bf16x8*)(qrow + g * 8);
        aq[1] = *(const bf16x8*)(qrow + 32 + g * 8);
    }

    // Stage tile 0
    #pragma unroll
    for (int it = 0; it < 2; ++it) {
        int rbase = wave * 16 + it * 8;
        int r = rbase + lr;
        gl2lds16(kg  + (size_t)r * DH + kbl * 8,      Ks + rbase * 64);
        gl2lds16(vtg + (size_t)r * LL + kbl * 8,      Vs + rbase * 64);
    }
    __syncthreads();

    f32x4 acc[4] = {};
    float lsum = 0.f;                   // row-sum for m = lm (this lane's 16 j)

    for (int kt = 0; kt < 16; ++kt) {
        unsigned short* Kc = Ks + (kt & 1) * (64 * 64);
        unsigned short* Vc = Vs + (kt & 1) * (64 * 64);
        if (kt + 1 < 16) {
            unsigned short* Kn = Ks + ((kt + 1) & 1) * (64 * 64);
            unsigned short* Vn = Vs + ((kt + 1) & 1) * (64 * 64);
            #pragma unroll
            for (int it = 0; it < 2; ++it) {
                int rbase = wave * 16 + it * 8;
                int r = rbase + lr;
                gl2lds16(kg  + (size_t)((kt + 1) * 64 + r) * DH + kbl * 8, Kn + rbase * 64);
                gl2lds16(vtg + (size_t)r * LL + (kt + 1) * 64 + kbl * 8,   Vn + rbase * 64);
            }
        }

        // S^T = K . Q^T : s[t][r] = S[m=lm][j = t*16 + g*4 + r]
        f32x4 s[4] = {};
        #pragma unroll
        for (int kk = 0; kk < 2; ++kk) {
            const int sw = ((kk * 4 + g) ^ (lm & 7)) * 8;
            #pragma unroll
            for (int t = 0; t < 4; ++t) {
                bf16x8 ak = *(const bf16x8*)&Kc[(t * 16 + lm) * 64 + sw];
                s[t] = __builtin_amdgcn_mfma_f32_16x16x32_bf16(ak, aq[kk], s[t], 0, 0, 0);
            }
        }

        // P = exp2(s); packed b64 write into [m][j] A-layout; per-lane row sum
        #pragma unroll
        for (int t = 0; t < 4; ++t) {
            u16x4 p4;
            #pragma unroll
            for (int r = 0; r < 4; ++r) {
                float p = exp2f(s[t][r]);
                lsum += p;
                p4[r] = f2bf(p);
            }
            *(u16x4*)&Pb[wave][lm * PSTR + t * 16 + g * 4] = p4;
        }
        // Pb wave-private: same-wave LDS ordering, no barrier needed

        // O += P V
        #pragma unroll
        for (int kk = 0; kk < 2; ++kk) {
            const int sw = ((kk * 4 + g) ^ (lm & 7)) * 8;
            bf16x8 ap = *(const bf16x8*)&Pb[wave][lm * PSTR + kk * 32 + g * 8];
            #pragma unroll
            for (int dt = 0; dt < 4; ++dt) {
                bf16x8 bv = *(const bf16x8*)&Vc[(dt * 16 + lm) * 64 + sw];
                acc[dt] = __builtin_amdgcn_mfma_f32_16x16x32_bf16(ap, bv, acc[dt], 0, 0, 0);
            }
        }
        __syncthreads();   // drains next-tile staging AFTER this tile's MFMAs
    }

    // Reduce row sums: lanes {lm, lm+16, lm+32, lm+48} hold partials for m=lm
    float ts = lsum;
    ts += __shfl_xor(ts, 16, 64);
    ts += __shfl_xor(ts, 32, 64);

    // Epilogue: lane's C rows are m = g*4+r; fetch their sums via shuffle
    int b = bh >> 4, h = bh & 15;
    #pragma unroll
    for (int r = 0; r < 4; ++r) {
        float inv = 1.f / __shfl(ts, g * 4 + r, 64);
        int qrow = qbase + wave * 16 + g * 4 + r;
        unsigned short* orow = ctx + (size_t)(b * LL + qrow) * DM + h * DH;
        #pragma unroll
        for (int dt = 0; dt < 4; ++dt)
            orow[dt * 16 + lm] = f2bf(acc[dt][r] * inv);
    }
}

// ---------------------------------------------------------------------------
extern "C" void kernel_launch(void* const* d_in, const int* in_sizes, int n_in,
                              void* d_out, int out_size, void* d_ws, size_t ws_size,
                              hipStream_t stream) {
    const float* queries = (const float*)d_in[0];
    const float* keys    = (const float*)d_in[1];
    const float* values  = (const float*)d_in[2];
    const float* Wq = (const float*)d_in[3];
    const float* bq = (const float*)d_in[4];
    const float* Wk = (const float*)d_in[5];
    const float* bk = (const float*)d_in[6];
    const float* Wv = (const float*)d_in[7];
    const float* bv = (const float*)d_in[8];
    const float* Wo = (const float*)d_in[9];
    const float* bo = (const float*)d_in[10];
    float* out = (float*)d_out;

    // Workspace (bf16 elements), 64 MB total. Rope tables (256 KB f32) live at
    // the head of the ctx region: consumed by gemm_qkv BEFORE attn writes ctx.
    unsigned short* qb   = (unsigned short*)d_ws;
    unsigned short* kb_  = qb  + (size_t)MM * DM;
    unsigned short* vb_  = kb_ + (size_t)MM * DM;
    unsigned short* Wqt  = vb_ + (size_t)MM * DM;
    unsigned short* Wkt  = Wqt + (size_t)DM * DM;
    unsigned short* Wvt  = Wkt + (size_t)DM * DM;
    unsigned short* Wot  = Wvt + (size_t)DM * DM;
    unsigned short* q_ws = Wot + (size_t)DM * DM;
    unsigned short* k_ws = q_ws + (size_t)MM * DM;
    unsigned short* vt   = k_ws + (size_t)MM * DM;
    unsigned short* ctx  = vt   + (size_t)MM * DM;
    float* rope_cos = (float*)ctx;                 // 32K floats
    float* rope_sin = rope_cos + LL * 32;          // 32K floats

    cvt_bf16_kernel<<<dim3(MM * DM / 1024, 1, 4), 256, 0, stream>>>(
        queries, keys, values, qb, kb_, vb_, rope_cos, rope_sin);
    transpose_w_kernel<<<dim3(32, 32, 4), 256, 0, stream>>>(
        Wq, Wk, Wv, Wo, Wqt, Wkt, Wvt, Wot);
    gemm_qkv_kernel<<<dim3(256, 1, 3), 256, 0, stream>>>(
        qb, kb_, vb_, Wqt, Wkt, Wvt, bq, bk, bv, rope_cos, rope_sin,
        q_ws, k_ws, vt);
    attn_mfma_kernel<<<dim3(LL / 64 * BB * HH), 256, 0, stream>>>(
        q_ws, k_ws, vt, ctx);
    gemm_out_kernel<<<dim3(256), 256, 0, stream>>>(
        ctx, Wot, bo, out);
}

// Round 8
// 224.273 us; speedup vs baseline: 1.0241x; 1.0241x over previous
//
#include <hip/hip_runtime.h>
#include <math.h>

// Problem constants (fixed by reference)
#define BB 4
#define LL 1024
#define HH 16
#define DH 64
#define DM 1024
#define MM (BB * LL)   // 4096 rows for the projections

typedef short bf16x8 __attribute__((ext_vector_type(8)));
typedef float f32x4  __attribute__((ext_vector_type(4)));
typedef unsigned short u16x4 __attribute__((ext_vector_type(4)));

__device__ __forceinline__ unsigned short f2bf(float x) {
    union { float f; unsigned u; } v; v.f = x;
    unsigned r = v.u + 0x7fff + ((v.u >> 16) & 1);   // round-to-nearest-even
    return (unsigned short)(r >> 16);
}

// async global->LDS, 16B per lane; LDS dest = wave-uniform base + lane*16
__device__ __forceinline__ void gl2lds16(const unsigned short* g, unsigned short* l) {
    __builtin_amdgcn_global_load_lds(
        (const __attribute__((address_space(1))) unsigned int*)g,
        (__attribute__((address_space(3))) unsigned int*)l, 16, 0, 0);
}

// XCD-aware tile mapping: blocks sharing an A-strip (same tM, 8 tN values)
// get linear ids congruent mod 8 -> same XCD -> A fetched once per strip.
__device__ __forceinline__ void tile_map(int n, int& tM, int& tN) {
    tM = ((n >> 6) * 8 + (n & 7)) * 128;
    tN = ((n >> 3) & 7) * 128;
}

// ---------------------------------------------------------------------------
// z in 0..2: f32 -> bf16 flat convert of queries/keys/values (4 elem/thread).
// z == 3  : rope cos/sin table (1024 x 32 each) — only first 32768 items.
// ---------------------------------------------------------------------------
__global__ __launch_bounds__(256) void cvt_bf16_kernel(
    const float* __restrict__ i0, const float* __restrict__ i1, const float* __restrict__ i2,
    unsigned short* __restrict__ o0, unsigned short* __restrict__ o1, unsigned short* __restrict__ o2,
    float* __restrict__ ct, float* __restrict__ st)
{
    int z = blockIdx.z;
    if (z == 3) {
        int idx = blockIdx.x * 256 + threadIdx.x;
        if (idx < LL * 32) {
            int l = idx >> 5, d = idx & 31;
            const float coef = -0.28782313662425583f;   // -ln(10000)/32
            float ang = (float)l * expf((float)d * coef);
            float s, c;
            sincosf(ang, &s, &c);
            ct[idx] = c;
            st[idx] = s;
        }
        return;
    }
    const float* in = (z == 0) ? i0 : (z == 1) ? i1 : i2;
    unsigned short* out = (z == 0) ? o0 : (z == 1) ? o1 : o2;
    int i = (blockIdx.x * 256 + threadIdx.x) * 4;
    float4 f = *(const float4*)(in + i);
    u16x4 r;
    r.x = f2bf(f.x); r.y = f2bf(f.y); r.z = f2bf(f.z); r.w = f2bf(f.w);
    *(u16x4*)(out + i) = r;
}

// ---------------------------------------------------------------------------
// W[K,N] f32 -> Wt[N,K] bf16 transpose (all 4 weights, z picks). 32x32 tiles.
// ---------------------------------------------------------------------------
__global__ __launch_bounds__(256) void transpose_w_kernel(
    const float* __restrict__ w0, const float* __restrict__ w1,
    const float* __restrict__ w2, const float* __restrict__ w3,
    unsigned short* __restrict__ t0, unsigned short* __restrict__ t1,
    unsigned short* __restrict__ t2, unsigned short* __restrict__ t3)
{
    int z = blockIdx.z;
    const float* in = (z == 0) ? w0 : (z == 1) ? w1 : (z == 2) ? w2 : w3;
    unsigned short* out = (z == 0) ? t0 : (z == 1) ? t1 : (z == 2) ? t2 : t3;
    __shared__ float tile[32][33];
    int tx = threadIdx.x & 31, ty = threadIdx.x >> 5;   // 32 x 8
    int c0 = blockIdx.x * 32, r0 = blockIdx.y * 32;
    #pragma unroll
    for (int j = 0; j < 32; j += 8)
        tile[ty + j][tx] = in[(size_t)(r0 + ty + j) * 1024 + c0 + tx];
    __syncthreads();
    #pragma unroll
    for (int j = 0; j < 32; j += 8)
        out[(size_t)(c0 + ty + j) * 1024 + r0 + tx] = f2bf(tile[tx][ty + j]);
}

// ---------------------------------------------------------------------------
// bf16 MFMA GEMM core, double-buffered: C128x128 += A[M,1024].Bt[N,1024]^T.
// BK=64, 2 LDS buffers per operand (64 KB total). Staging for tile kt+1 is
// issued BEFORE computing tile kt. LDS unpadded, XOR-swizzled (kb^row&7).
// ---------------------------------------------------------------------------
__device__ __forceinline__ void stage_tile(
    const unsigned short* __restrict__ A, const unsigned short* __restrict__ Bt,
    unsigned short* As, unsigned short* Bs, int tM, int tN, int kt,
    int wave, int lr, int kbl)
{
    const int k0 = kt * 64;
    #pragma unroll
    for (int it = 0; it < 4; ++it) {
        int rbase = wave * 32 + it * 8;
        int r = rbase + lr;
        gl2lds16(A  + (size_t)(tM + r) * 1024 + k0 + kbl * 8, As + rbase * 64);
        gl2lds16(Bt + (size_t)(tN + r) * 1024 + k0 + kbl * 8, Bs + rbase * 64);
    }
}

__device__ __forceinline__ void gemm128_core(
    const unsigned short* __restrict__ A, const unsigned short* __restrict__ Bt,
    unsigned short* As, unsigned short* Bs,   // each 2 x 128*64
    int tM, int tN, f32x4 (&acc)[4][4])
{
    const int tid  = threadIdx.x;
    const int wave = tid >> 6, lane = tid & 63;
    const int g = lane >> 4, lm = lane & 15;
    const int wm = wave >> 1, wn = wave & 1;
    const int lr = lane >> 3, lk = lane & 7;
    const int kbl = lk ^ lr;                    // swizzled k-block for staging

    stage_tile(A, Bt, As, Bs, tM, tN, 0, wave, lr, kbl);
    __syncthreads();

    for (int kt = 0; kt < 16; ++kt) {
        unsigned short* Ac = As + (kt & 1) * (128 * 64);
        unsigned short* Bc = Bs + (kt & 1) * (128 * 64);
        if (kt + 1 < 16) {
            unsigned short* An = As + ((kt + 1) & 1) * (128 * 64);
            unsigned short* Bn = Bs + ((kt + 1) & 1) * (128 * 64);
            stage_tile(A, Bt, An, Bn, tM, tN, kt + 1, wave, lr, kbl);
        }

        #pragma unroll
        for (int kk = 0; kk < 2; ++kk) {
            bf16x8 a[4], b[4];
            const int sw = ((kk * 4 + g) ^ (lm & 7)) * 8;
            #pragma unroll
            for (int mt = 0; mt < 4; ++mt)
                a[mt] = *(const bf16x8*)&Ac[(wm * 64 + mt * 16 + lm) * 64 + sw];
            #pragma unroll
            for (int nt = 0; nt < 4; ++nt)
                b[nt] = *(const bf16x8*)&Bc[(wn * 64 + nt * 16 + lm) * 64 + sw];
            #pragma unroll
            for (int mt = 0; mt < 4; ++mt)
                #pragma unroll
                for (int nt = 0; nt < 4; ++nt)
                    acc[mt][nt] = __builtin_amdgcn_mfma_f32_16x16x32_bf16(
                        a[mt], b[nt], acc[mt][nt], 0, 0, 0);
        }
        __syncthreads();   // drains this iter's staging AFTER the MFMAs
    }
}

// ---------------------------------------------------------------------------
// QKV projections, fused over blockIdx.z (0=q rope+scale, 1=k rope, 2=v).
// Q scale = 0.125 * log2(e) so attention uses a single exp2.
// Rope cos/sin from precomputed tables. z==2 writes V^T [bh][d][l] (b64).
// grid (256, 1, 3) with XCD tile_map.
// ---------------------------------------------------------------------------
__global__ __launch_bounds__(256) void gemm_qkv_kernel(
    const unsigned short* __restrict__ Aq, const unsigned short* __restrict__ Ak,
    const unsigned short* __restrict__ Av,
    const unsigned short* __restrict__ Wqt, const unsigned short* __restrict__ Wkt,
    const unsigned short* __restrict__ Wvt,
    const float* __restrict__ bq, const float* __restrict__ bk, const float* __restrict__ bv,
    const float* __restrict__ ct, const float* __restrict__ st,
    unsigned short* __restrict__ oq, unsigned short* __restrict__ ok,
    unsigned short* __restrict__ vt)
{
    __shared__ __align__(16) unsigned short As[2 * 128 * 64];
    __shared__ __align__(16) unsigned short Bs[2 * 128 * 64];

    const int z = blockIdx.z;
    const unsigned short* A  = (z == 0) ? Aq  : (z == 1) ? Ak  : Av;
    const unsigned short* Bt = (z == 0) ? Wqt : (z == 1) ? Wkt : Wvt;
    const float* bias        = (z == 0) ? bq  : (z == 1) ? bk  : bv;

    int tM, tN;
    tile_map(blockIdx.x, tM, tN);
    f32x4 acc[4][4] = {};
    gemm128_core(A, Bt, As, Bs, tM, tN, acc);

    const int wave = threadIdx.x >> 6, lane = threadIdx.x & 63;
    const int g = lane >> 4, lm = lane & 15;
    const int wm = wave >> 1, wn = wave & 1;

    const int colbase = tN + wn * 64;           // head-aligned (64 cols/wave)
    const int h = colbase >> 6;
    float bvv[4];
    #pragma unroll
    for (int nt = 0; nt < 4; ++nt) bvv[nt] = bias[colbase + nt * 16 + lm];

    if (z == 2) {                               // V: write V^T [bh][d][l], b64
        #pragma unroll
        for (int mt = 0; mt < 4; ++mt) {
            int row0 = tM + wm * 64 + mt * 16 + g * 4;   // 4 consecutive rows
            int b = row0 >> 10, l0 = row0 & 1023;
            #pragma unroll
            for (int nt = 0; nt < 4; ++nt) {
                int dloc = nt * 16 + lm;
                u16x4 p4;
                #pragma unroll
                for (int r = 0; r < 4; ++r)
                    p4[r] = f2bf(acc[mt][nt][r] + bvv[nt]);
                *(u16x4*)(vt + (((size_t)(b * HH + h) * DH + dloc) << 10) + l0) = p4;
            }
        }
    } else {                                    // Q/K: rope from table
        unsigned short* out = (z == 0) ? oq : ok;
        const float sc = (z == 0) ? 0.125f * 1.4426950408889634f : 1.0f;
        #pragma unroll
        for (int mt = 0; mt < 4; ++mt)
            #pragma unroll
            for (int r = 0; r < 4; ++r) {
                int row = tM + wm * 64 + mt * 16 + g * 4 + r;
                int b = row >> 10, l = row & 1023;
                const float* cl = ct + l * 32;
                const float* sl = st + l * 32;
                unsigned short* orow = out + ((size_t)(b * HH + h) * LL + l) * DH;
                #pragma unroll
                for (int nt = 0; nt < 2; ++nt) {
                    float t1 = acc[mt][nt][r]     + bvv[nt];
                    float t2 = acc[mt][nt + 2][r] + bvv[nt + 2];
                    float c = cl[nt * 16 + lm];
                    float s = sl[nt * 16 + lm];
                    orow[nt * 16 + lm]      = f2bf((t1 * c - t2 * s) * sc);
                    orow[nt * 16 + lm + 32] = f2bf((t1 * s + t2 * c) * sc);
                }
            }
    }
}

// ---------------------------------------------------------------------------
// Output projection: f32 C = ctx(bf16) . Wot^T + bo. grid (256), XCD tile_map.
// ---------------------------------------------------------------------------
__global__ __launch_bounds__(256) void gemm_out_kernel(
    const unsigned short* __restrict__ A, const unsigned short* __restrict__ Bt,
    const float* __restrict__ bias, float* __restrict__ C)
{
    __shared__ __align__(16) unsigned short As[2 * 128 * 64];
    __shared__ __align__(16) unsigned short Bs[2 * 128 * 64];

    int tM, tN;
    tile_map(blockIdx.x, tM, tN);
    f32x4 acc[4][4] = {};
    gemm128_core(A, Bt, As, Bs, tM, tN, acc);

    const int wave = threadIdx.x >> 6, lane = threadIdx.x & 63;
    const int g = lane >> 4, lm = lane & 15;
    const int wm = wave >> 1, wn = wave & 1;

    float bvv[4];
    #pragma unroll
    for (int nt = 0; nt < 4; ++nt) bvv[nt] = bias[tN + wn * 64 + nt * 16 + lm];
    #pragma unroll
    for (int mt = 0; mt < 4; ++mt)
        #pragma unroll
        for (int r = 0; r < 4; ++r) {
            int row = tM + wm * 64 + mt * 16 + g * 4 + r;
            float* crow = C + (size_t)row * DM + tN + wn * 64;
            #pragma unroll
            for (int nt = 0; nt < 4; ++nt)
                crow[nt * 16 + lm] = acc[mt][nt][r] + bvv[nt];
        }
}

// ---------------------------------------------------------------------------
// Flash-style bf16 MFMA attention, S^T formulation, SINGLE-buffered staging
// (round-5 form: dbuf costs occupancy 30->20% here and regressed 46->54 us).
// S^T = K.Q^T; MFMA C-layout gives each lane 4 consecutive j for fixed m=lm:
// P goes to LDS [m][j] with packed ds_write_b64, read back as PV A-frags.
// Row sums: one scalar per lane, reduced with 2 shuffles at the end.
// 1-D grid, bh = n&63 so each head's 16 blocks share an XCD (L2 locality).
// ---------------------------------------------------------------------------
#define PSTR 72

__global__ __launch_bounds__(256) void attn_mfma_kernel(
    const unsigned short* __restrict__ q, const unsigned short* __restrict__ k,
    const unsigned short* __restrict__ vt, unsigned short* __restrict__ ctx)
{
    __shared__ __align__(16) unsigned short Ks[64 * 64];
    __shared__ __align__(16) unsigned short Vs[64 * 64];
    __shared__ __align__(16) unsigned short Pb[4][16 * PSTR];

    const int tid  = threadIdx.x;
    const int wave = tid >> 6, lane = tid & 63;
    const int g = lane >> 4, lm = lane & 15;
    const int lr = lane >> 3, lk = lane & 7;
    const int kbl = lk ^ lr;
    const int n = blockIdx.x;
    const int bh = n & 63;              // XCD-swizzle: bh%8 == n%8 == XCD
    const int qbase = (n >> 6) * 64;

    const unsigned short* qg  = q  + (size_t)(bh * LL + qbase) * DH;
    const unsigned short* kg  = k  + (size_t)bh * LL * DH;
    const unsigned short* vtg = vt + (size_t)bh * DH * LL;   // [64 d][1024 l]

    bf16x8 aq[2];
    {
        const unsigned short* qrow = qg + (wave * 16 + lm) * DH;
        aq[0] = *(const bf16x8*)(qrow + g * 8);
        aq[1] = *(const bf16x8*)(qrow + 32 + g * 8);
    }

    f32x4 acc[4] = {};
    float lsum = 0.f;                   // row-sum for m = lm (this lane's 16 j)

    for (int kt = 0; kt < 16; ++kt) {
        if (kt) __syncthreads();
        #pragma unroll
        for (int it = 0; it < 2; ++it) {
            int rbase = wave * 16 + it * 8;
            int r = rbase + lr;
            gl2lds16(kg  + (size_t)(kt * 64 + r) * DH + kbl * 8, Ks + rbase * 64);
            gl2lds16(vtg + (size_t)r * LL + kt * 64 + kbl * 8,  Vs + rbase * 64);
        }
        __syncthreads();

        // S^T = K . Q^T : s[t][r] = S[m=lm][j = t*16 + g*4 + r]
        f32x4 s[4] = {};
        #pragma unroll
        for (int kk = 0; kk < 2; ++kk) {
            const int sw = ((kk * 4 + g) ^ (lm & 7)) * 8;
            #pragma unroll
            for (int t = 0; t < 4; ++t) {
                bf16x8 ak = *(const bf16x8*)&Ks[(t * 16 + lm) * 64 + sw];
                s[t] = __builtin_amdgcn_mfma_f32_16x16x32_bf16(ak, aq[kk], s[t], 0, 0, 0);
            }
        }

        // P = exp2(s); packed b64 write into [m][j] A-layout; per-lane row sum
        #pragma unroll
        for (int t = 0; t < 4; ++t) {
            u16x4 p4;
            #pragma unroll
            for (int r = 0; r < 4; ++r) {
                float p = exp2f(s[t][r]);
                lsum += p;
                p4[r] = f2bf(p);
            }
            *(u16x4*)&Pb[wave][lm * PSTR + t * 16 + g * 4] = p4;
        }
        // Pb wave-private: same-wave LDS ordering, no barrier needed

        // O += P V
        #pragma unroll
        for (int kk = 0; kk < 2; ++kk) {
            const int sw = ((kk * 4 + g) ^ (lm & 7)) * 8;
            bf16x8 ap = *(const bf16x8*)&Pb[wave][lm * PSTR + kk * 32 + g * 8];
            #pragma unroll
            for (int dt = 0; dt < 4; ++dt) {
                bf16x8 bv = *(const bf16x8*)&Vs[(dt * 16 + lm) * 64 + sw];
                acc[dt] = __builtin_amdgcn_mfma_f32_16x16x32_bf16(ap, bv, acc[dt], 0, 0, 0);
            }
        }
    }

    // Reduce row sums: lanes {lm, lm+16, lm+32, lm+48} hold partials for m=lm
    float ts = lsum;
    ts += __shfl_xor(ts, 16, 64);
    ts += __shfl_xor(ts, 32, 64);

    // Epilogue: lane's C rows are m = g*4+r; fetch their sums via shuffle
    int b = bh >> 4, h = bh & 15;
    #pragma unroll
    for (int r = 0; r < 4; ++r) {
        float inv = 1.f / __shfl(ts, g * 4 + r, 64);
        int qrow = qbase + wave * 16 + g * 4 + r;
        unsigned short* orow = ctx + (size_t)(b * LL + qrow) * DM + h * DH;
        #pragma unroll
        for (int dt = 0; dt < 4; ++dt)
            orow[dt * 16 + lm] = f2bf(acc[dt][r] * inv);
    }
}

// ---------------------------------------------------------------------------
extern "C" void kernel_launch(void* const* d_in, const int* in_sizes, int n_in,
                              void* d_out, int out_size, void* d_ws, size_t ws_size,
                              hipStream_t stream) {
    const float* queries = (const float*)d_in[0];
    const float* keys    = (const float*)d_in[1];
    const float* values  = (const float*)d_in[2];
    const float* Wq = (const float*)d_in[3];
    const float* bq = (const float*)d_in[4];
    const float* Wk = (const float*)d_in[5];
    const float* bk = (const float*)d_in[6];
    const float* Wv = (const float*)d_in[7];
    const float* bv = (const float*)d_in[8];
    const float* Wo = (const float*)d_in[9];
    const float* bo = (const float*)d_in[10];
    float* out = (float*)d_out;

    // Workspace (bf16 elements), 64 MB total. Rope tables (256 KB f32) live at
    // the head of the ctx region: consumed by gemm_qkv BEFORE attn writes ctx.
    unsigned short* qb   = (unsigned short*)d_ws;
    unsigned short* kb_  = qb  + (size_t)MM * DM;
    unsigned short* vb_  = kb_ + (size_t)MM * DM;
    unsigned short* Wqt  = vb_ + (size_t)MM * DM;
    unsigned short* Wkt  = Wqt + (size_t)DM * DM;
    unsigned short* Wvt  = Wkt + (size_t)DM * DM;
    unsigned short* Wot  = Wvt + (size_t)DM * DM;
    unsigned short* q_ws = Wot + (size_t)DM * DM;
    unsigned short* k_ws = q_ws + (size_t)MM * DM;
    unsigned short* vt   = k_ws + (size_t)MM * DM;
    unsigned short* ctx  = vt   + (size_t)MM * DM;
    float* rope_cos = (float*)ctx;                 // 32K floats
    float* rope_sin = rope_cos + LL * 32;          // 32K floats

    cvt_bf16_kernel<<<dim3(MM * DM / 1024, 1, 4), 256, 0, stream>>>(
        queries, keys, values, qb, kb_, vb_, rope_cos, rope_sin);
    transpose_w_kernel<<<dim3(32, 32, 4), 256, 0, stream>>>(
        Wq, Wk, Wv, Wo, Wqt, Wkt, Wvt, Wot);
    gemm_qkv_kernel<<<dim3(256, 1, 3), 256, 0, stream>>>(
        qb, kb_, vb_, Wqt, Wkt, Wvt, bq, bk, bv, rope_cos, rope_sin,
        q_ws, k_ws, vt);
    attn_mfma_kernel<<<dim3(LL / 64 * BB * HH), 256, 0, stream>>>(
        q_ws, k_ws, vt, ctx);
    gemm_out_kernel<<<dim3(256), 256, 0, stream>>>(
        ctx, Wot, bo, out);
}

// Round 9
// 215.389 us; speedup vs baseline: 1.0664x; 1.0412x over previous
//
#include <hip/hip_runtime.h>
#include <math.h>

// Problem constants (fixed by reference)
#define BB 4
#define LL 1024
#define HH 16
#define DH 64
#define DM 1024
#define MM (BB * LL)   // 4096 rows for the projections

typedef short bf16x8 __attribute__((ext_vector_type(8)));
typedef float f32x4  __attribute__((ext_vector_type(4)));
typedef unsigned short u16x4 __attribute__((ext_vector_type(4)));

__device__ __forceinline__ unsigned short f2bf(float x) {
    union { float f; unsigned u; } v; v.f = x;
    unsigned r = v.u + 0x7fff + ((v.u >> 16) & 1);   // round-to-nearest-even
    return (unsigned short)(r >> 16);
}

// async global->LDS, 16B per lane; LDS dest = wave-uniform base + lane*16
__device__ __forceinline__ void gl2lds16(const unsigned short* g, unsigned short* l) {
    __builtin_amdgcn_global_load_lds(
        (const __attribute__((address_space(1))) unsigned int*)g,
        (__attribute__((address_space(3))) unsigned int*)l, 16, 0, 0);
}

// XCD-aware tile mapping: blocks sharing an A-strip (same tM, 8 tN values)
// get linear ids congruent mod 8 -> same XCD -> A fetched once per strip.
__device__ __forceinline__ void tile_map(int n, int& tM, int& tN) {
    tM = ((n >> 6) * 8 + (n & 7)) * 128;
    tN = ((n >> 3) & 7) * 128;
}

// ---------------------------------------------------------------------------
// Fused prep kernel, grid (1024, 1, 8):
//  z 0..2 : f32 -> bf16 flat convert of queries/keys/values (16 elem/thread)
//  z == 3 : rope cos/sin table (1024 l x 32 d) — first 128 blocks only
//  z 4..7 : W[K,N] f32 -> Wt[N,K] bf16 transpose, 32x32 tiles (1024 blocks)
// ---------------------------------------------------------------------------
__global__ __launch_bounds__(256) void prep_kernel(
    const float* __restrict__ i0, const float* __restrict__ i1, const float* __restrict__ i2,
    unsigned short* __restrict__ o0, unsigned short* __restrict__ o1, unsigned short* __restrict__ o2,
    const float* __restrict__ w0, const float* __restrict__ w1,
    const float* __restrict__ w2, const float* __restrict__ w3,
    unsigned short* __restrict__ t0, unsigned short* __restrict__ t1,
    unsigned short* __restrict__ t2, unsigned short* __restrict__ t3,
    float* __restrict__ ct, float* __restrict__ st)
{
    const int z = blockIdx.z;
    const int bid = blockIdx.x, tid = threadIdx.x;

    if (z < 3) {
        const float* in = (z == 0) ? i0 : (z == 1) ? i1 : i2;
        unsigned short* out = (z == 0) ? o0 : (z == 1) ? o1 : o2;
        #pragma unroll
        for (int it = 0; it < 4; ++it) {
            size_t i = ((size_t)(it * 1024 + bid) * 256 + tid) * 4;
            float4 f = *(const float4*)(in + i);
            u16x4 r;
            r.x = f2bf(f.x); r.y = f2bf(f.y); r.z = f2bf(f.z); r.w = f2bf(f.w);
            *(u16x4*)(out + i) = r;
        }
    } else if (z == 3) {
        int idx = bid * 256 + tid;
        if (idx < LL * 32) {
            int l = idx >> 5, d = idx & 31;
            const float coef = -0.28782313662425583f;   // -ln(10000)/32
            float ang = (float)l * expf((float)d * coef);
            float s, c;
            sincosf(ang, &s, &c);
            ct[idx] = c;
            st[idx] = s;
        }
    } else {
        const int w = z - 4;
        const float* in = (w == 0) ? w0 : (w == 1) ? w1 : (w == 2) ? w2 : w3;
        unsigned short* out = (w == 0) ? t0 : (w == 1) ? t1 : (w == 2) ? t2 : t3;
        __shared__ float tile[32][33];
        int tx = tid & 31, ty = tid >> 5;   // 32 x 8
        int c0 = (bid & 31) * 32, r0 = (bid >> 5) * 32;
        #pragma unroll
        for (int j = 0; j < 32; j += 8)
            tile[ty + j][tx] = in[(size_t)(r0 + ty + j) * 1024 + c0 + tx];
        __syncthreads();
        #pragma unroll
        for (int j = 0; j < 32; j += 8)
            out[(size_t)(c0 + ty + j) * 1024 + r0 + tx] = f2bf(tile[tx][ty + j]);
    }
}

// ---------------------------------------------------------------------------
// bf16 MFMA GEMM core, SINGLE-buffered (dbuf at 64 KB LDS = 2 blocks/CU
// measured 47->67 us regression; single-buf 32 KB keeps ~5 blocks/CU).
// C128x128 += A[M,1024] . Bt[N,1024]^T, BK=64. LDS unpadded, XOR-swizzled
// (kb_phys = kb ^ (row&7)); 4 waves in 2x2, each 64x64.
// ---------------------------------------------------------------------------
__device__ __forceinline__ void gemm128_sb(
    const unsigned short* __restrict__ A, const unsigned short* __restrict__ Bt,
    unsigned short* As, unsigned short* Bs, int tM, int tN, f32x4 (&acc)[4][4])
{
    const int tid  = threadIdx.x;
    const int wave = tid >> 6, lane = tid & 63;
    const int g = lane >> 4, lm = lane & 15;
    const int wm = wave >> 1, wn = wave & 1;
    const int lr = lane >> 3, lk = lane & 7;
    const int kbl = lk ^ lr;                    // swizzled k-block for staging

    for (int kt = 0; kt < 16; ++kt) {
        const int k0 = kt * 64;
        if (kt) __syncthreads();
        #pragma unroll
        for (int it = 0; it < 4; ++it) {
            int rbase = wave * 32 + it * 8;
            int r = rbase + lr;
            gl2lds16(A  + (size_t)(tM + r) * 1024 + k0 + kbl * 8, As + rbase * 64);
            gl2lds16(Bt + (size_t)(tN + r) * 1024 + k0 + kbl * 8, Bs + rbase * 64);
        }
        __syncthreads();

        #pragma unroll
        for (int kk = 0; kk < 2; ++kk) {
            bf16x8 a[4], b[4];
            const int sw = ((kk * 4 + g) ^ (lm & 7)) * 8;
            #pragma unroll
            for (int mt = 0; mt < 4; ++mt)
                a[mt] = *(const bf16x8*)&As[(wm * 64 + mt * 16 + lm) * 64 + sw];
            #pragma unroll
            for (int nt = 0; nt < 4; ++nt)
                b[nt] = *(const bf16x8*)&Bs[(wn * 64 + nt * 16 + lm) * 64 + sw];
            #pragma unroll
            for (int mt = 0; mt < 4; ++mt)
                #pragma unroll
                for (int nt = 0; nt < 4; ++nt)
                    acc[mt][nt] = __builtin_amdgcn_mfma_f32_16x16x32_bf16(
                        a[mt], b[nt], acc[mt][nt], 0, 0, 0);
        }
    }
}

// ---------------------------------------------------------------------------
// QKV projections, fused over blockIdx.z (0=q rope+scale, 1=k rope, 2=v).
// Q scale = 0.125 * log2(e) so attention uses a single exp2.
// Rope cos/sin from precomputed tables. z==2 writes V^T [bh][d][l] (b64).
// grid (256, 1, 3) with XCD tile_map.
// ---------------------------------------------------------------------------
__global__ __launch_bounds__(256) void gemm_qkv_kernel(
    const unsigned short* __restrict__ Aq, const unsigned short* __restrict__ Ak,
    const unsigned short* __restrict__ Av,
    const unsigned short* __restrict__ Wqt, const unsigned short* __restrict__ Wkt,
    const unsigned short* __restrict__ Wvt,
    const float* __restrict__ bq, const float* __restrict__ bk, const float* __restrict__ bv,
    const float* __restrict__ ct, const float* __restrict__ st,
    unsigned short* __restrict__ oq, unsigned short* __restrict__ ok,
    unsigned short* __restrict__ vt)
{
    __shared__ __align__(16) unsigned short As[128 * 64];
    __shared__ __align__(16) unsigned short Bs[128 * 64];

    const int z = blockIdx.z;
    const unsigned short* A  = (z == 0) ? Aq  : (z == 1) ? Ak  : Av;
    const unsigned short* Bt = (z == 0) ? Wqt : (z == 1) ? Wkt : Wvt;
    const float* bias        = (z == 0) ? bq  : (z == 1) ? bk  : bv;

    int tM, tN;
    tile_map(blockIdx.x, tM, tN);
    f32x4 acc[4][4] = {};
    gemm128_sb(A, Bt, As, Bs, tM, tN, acc);

    const int wave = threadIdx.x >> 6, lane = threadIdx.x & 63;
    const int g = lane >> 4, lm = lane & 15;
    const int wm = wave >> 1, wn = wave & 1;

    const int colbase = tN + wn * 64;           // head-aligned (64 cols/wave)
    const int h = colbase >> 6;
    float bvv[4];
    #pragma unroll
    for (int nt = 0; nt < 4; ++nt) bvv[nt] = bias[colbase + nt * 16 + lm];

    if (z == 2) {                               // V: write V^T [bh][d][l], b64
        #pragma unroll
        for (int mt = 0; mt < 4; ++mt) {
            int row0 = tM + wm * 64 + mt * 16 + g * 4;   // 4 consecutive rows
            int b = row0 >> 10, l0 = row0 & 1023;
            #pragma unroll
            for (int nt = 0; nt < 4; ++nt) {
                int dloc = nt * 16 + lm;
                u16x4 p4;
                #pragma unroll
                for (int r = 0; r < 4; ++r)
                    p4[r] = f2bf(acc[mt][nt][r] + bvv[nt]);
                *(u16x4*)(vt + (((size_t)(b * HH + h) * DH + dloc) << 10) + l0) = p4;
            }
        }
    } else {                                    // Q/K: rope from table
        unsigned short* out = (z == 0) ? oq : ok;
        const float sc = (z == 0) ? 0.125f * 1.4426950408889634f : 1.0f;
        #pragma unroll
        for (int mt = 0; mt < 4; ++mt)
            #pragma unroll
            for (int r = 0; r < 4; ++r) {
                int row = tM + wm * 64 + mt * 16 + g * 4 + r;
                int b = row >> 10, l = row & 1023;
                const float* cl = ct + l * 32;
                const float* sl = st + l * 32;
                unsigned short* orow = out + ((size_t)(b * HH + h) * LL + l) * DH;
                #pragma unroll
                for (int nt = 0; nt < 2; ++nt) {
                    float t1 = acc[mt][nt][r]     + bvv[nt];
                    float t2 = acc[mt][nt + 2][r] + bvv[nt + 2];
                    float c = cl[nt * 16 + lm];
                    float s = sl[nt * 16 + lm];
                    orow[nt * 16 + lm]      = f2bf((t1 * c - t2 * s) * sc);
                    orow[nt * 16 + lm + 32] = f2bf((t1 * s + t2 * c) * sc);
                }
            }
    }
}

// ---------------------------------------------------------------------------
// Output projection: f32 C = ctx(bf16) . Wot^T + bo. grid (256), XCD tile_map.
// ---------------------------------------------------------------------------
__global__ __launch_bounds__(256) void gemm_out_kernel(
    const unsigned short* __restrict__ A, const unsigned short* __restrict__ Bt,
    const float* __restrict__ bias, float* __restrict__ C)
{
    __shared__ __align__(16) unsigned short As[128 * 64];
    __shared__ __align__(16) unsigned short Bs[128 * 64];

    int tM, tN;
    tile_map(blockIdx.x, tM, tN);
    f32x4 acc[4][4] = {};
    gemm128_sb(A, Bt, As, Bs, tM, tN, acc);

    const int wave = threadIdx.x >> 6, lane = threadIdx.x & 63;
    const int g = lane >> 4, lm = lane & 15;
    const int wm = wave >> 1, wn = wave & 1;

    float bvv[4];
    #pragma unroll
    for (int nt = 0; nt < 4; ++nt) bvv[nt] = bias[tN + wn * 64 + nt * 16 + lm];
    #pragma unroll
    for (int mt = 0; mt < 4; ++mt)
        #pragma unroll
        for (int r = 0; r < 4; ++r) {
            int row = tM + wm * 64 + mt * 16 + g * 4 + r;
            float* crow = C + (size_t)row * DM + tN + wn * 64;
            #pragma unroll
            for (int nt = 0; nt < 4; ++nt)
                crow[nt * 16 + lm] = acc[mt][nt][r] + bvv[nt];
        }
}

// ---------------------------------------------------------------------------
// Flash-style bf16 MFMA attention, S^T formulation, single-buffered staging.
// S^T = K.Q^T; MFMA C-layout gives each lane 4 consecutive j for fixed m=lm:
// P goes to LDS [m][j] with packed ds_write_b64, read back as PV A-frags.
// Row sums: one scalar per lane, reduced with 2 shuffles at the end.
// 1-D grid, bh = n&63 so each head's 16 blocks share an XCD (L2 locality).
// ---------------------------------------------------------------------------
#define PSTR 72

__global__ __launch_bounds__(256) void attn_mfma_kernel(
    const unsigned short* __restrict__ q, const unsigned short* __restrict__ k,
    const unsigned short* __restrict__ vt, unsigned short* __restrict__ ctx)
{
    __shared__ __align__(16) unsigned short Ks[64 * 64];
    __shared__ __align__(16) unsigned short Vs[64 * 64];
    __shared__ __align__(16) unsigned short Pb[4][16 * PSTR];

    const int tid  = threadIdx.x;
    const int wave = tid >> 6, lane = tid & 63;
    const int g = lane >> 4, lm = lane & 15;
    const int lr = lane >> 3, lk = lane & 7;
    const int kbl = lk ^ lr;
    const int n = blockIdx.x;
    const int bh = n & 63;              // XCD-swizzle: bh%8 == n%8 == XCD
    const int qbase = (n >> 6) * 64;

    const unsigned short* qg  = q  + (size_t)(bh * LL + qbase) * DH;
    const unsigned short* kg  = k  + (size_t)bh * LL * DH;
    const unsigned short* vtg = vt + (size_t)bh * DH * LL;   // [64 d][1024 l]

    bf16x8 aq[2];
    {
        const unsigned short* qrow = qg + (wave * 16 + lm) * DH;
        aq[0] = *(const bf16x8*)(qrow + g * 8);
        aq[1] = *(const bf16x8*)(qrow + 32 + g * 8);
    }

    f32x4 acc[4] = {};
    float lsum = 0.f;                   // row-sum for m = lm (this lane's 16 j)

    for (int kt = 0; kt < 16; ++kt) {
        if (kt) __syncthreads();
        #pragma unroll
        for (int it = 0; it < 2; ++it) {
            int rbase = wave * 16 + it * 8;
            int r = rbase + lr;
            gl2lds16(kg  + (size_t)(kt * 64 + r) * DH + kbl * 8, Ks + rbase * 64);
            gl2lds16(vtg + (size_t)r * LL + kt * 64 + kbl * 8,  Vs + rbase * 64);
        }
        __syncthreads();

        // S^T = K . Q^T : s[t][r] = S[m=lm][j = t*16 + g*4 + r]
        f32x4 s[4] = {};
        #pragma unroll
        for (int kk = 0; kk < 2; ++kk) {
            const int sw = ((kk * 4 + g) ^ (lm & 7)) * 8;
            #pragma unroll
            for (int t = 0; t < 4; ++t) {
                bf16x8 ak = *(const bf16x8*)&Ks[(t * 16 + lm) * 64 + sw];
                s[t] = __builtin_amdgcn_mfma_f32_16x16x32_bf16(ak, aq[kk], s[t], 0, 0, 0);
            }
        }

        // P = exp2(s); packed b64 write into [m][j] A-layout; per-lane row sum
        #pragma unroll
        for (int t = 0; t < 4; ++t) {
            u16x4 p4;
            #pragma unroll
            for (int r = 0; r < 4; ++r) {
                float p = exp2f(s[t][r]);
                lsum += p;
                p4[r] = f2bf(p);
            }
            *(u16x4*)&Pb[wave][lm * PSTR + t * 16 + g * 4] = p4;
        }
        // Pb wave-private: same-wave LDS ordering, no barrier needed

        // O += P V
        #pragma unroll
        for (int kk = 0; kk < 2; ++kk) {
            const int sw = ((kk * 4 + g) ^ (lm & 7)) * 8;
            bf16x8 ap = *(const bf16x8*)&Pb[wave][lm * PSTR + kk * 32 + g * 8];
            #pragma unroll
            for (int dt = 0; dt < 4; ++dt) {
                bf16x8 bv = *(const bf16x8*)&Vs[(dt * 16 + lm) * 64 + sw];
                acc[dt] = __builtin_amdgcn_mfma_f32_16x16x32_bf16(ap, bv, acc[dt], 0, 0, 0);
            }
        }
    }

    // Reduce row sums: lanes {lm, lm+16, lm+32, lm+48} hold partials for m=lm
    float ts = lsum;
    ts += __shfl_xor(ts, 16, 64);
    ts += __shfl_xor(ts, 32, 64);

    // Epilogue: lane's C rows are m = g*4+r; fetch their sums via shuffle
    int b = bh >> 4, h = bh & 15;
    #pragma unroll
    for (int r = 0; r < 4; ++r) {
        float inv = 1.f / __shfl(ts, g * 4 + r, 64);
        int qrow = qbase + wave * 16 + g * 4 + r;
        unsigned short* orow = ctx + (size_t)(b * LL + qrow) * DM + h * DH;
        #pragma unroll
        for (int dt = 0; dt < 4; ++dt)
            orow[dt * 16 + lm] = f2bf(acc[dt][r] * inv);
    }
}

// ---------------------------------------------------------------------------
extern "C" void kernel_launch(void* const* d_in, const int* in_sizes, int n_in,
                              void* d_out, int out_size, void* d_ws, size_t ws_size,
                              hipStream_t stream) {
    const float* queries = (const float*)d_in[0];
    const float* keys    = (const float*)d_in[1];
    const float* values  = (const float*)d_in[2];
    const float* Wq = (const float*)d_in[3];
    const float* bq = (const float*)d_in[4];
    const float* Wk = (const float*)d_in[5];
    const float* bk = (const float*)d_in[6];
    const float* Wv = (const float*)d_in[7];
    const float* bv = (const float*)d_in[8];
    const float* Wo = (const float*)d_in[9];
    const float* bo = (const float*)d_in[10];
    float* out = (float*)d_out;

    // Workspace (bf16 elements), 64 MB total. Rope tables (256 KB f32) live at
    // the head of the ctx region: consumed by gemm_qkv BEFORE attn writes ctx.
    unsigned short* qb   = (unsigned short*)d_ws;
    unsigned short* kb_  = qb  + (size_t)MM * DM;
    unsigned short* vb_  = kb_ + (size_t)MM * DM;
    unsigned short* Wqt  = vb_ + (size_t)MM * DM;
    unsigned short* Wkt  = Wqt + (size_t)DM * DM;
    unsigned short* Wvt  = Wkt + (size_t)DM * DM;
    unsigned short* Wot  = Wvt + (size_t)DM * DM;
    unsigned short* q_ws = Wot + (size_t)DM * DM;
    unsigned short* k_ws = q_ws + (size_t)MM * DM;
    unsigned short* vt   = k_ws + (size_t)MM * DM;
    unsigned short* ctx  = vt   + (size_t)MM * DM;
    float* rope_cos = (float*)ctx;                 // 32K floats
    float* rope_sin = rope_cos + LL * 32;          // 32K floats

    prep_kernel<<<dim3(1024, 1, 8), 256, 0, stream>>>(
        queries, keys, values, qb, kb_, vb_,
        Wq, Wk, Wv, Wo, Wqt, Wkt, Wvt, Wot, rope_cos, rope_sin);
    gemm_qkv_kernel<<<dim3(256, 1, 3), 256, 0, stream>>>(
        qb, kb_, vb_, Wqt, Wkt, Wvt, bq, bk, bv, rope_cos, rope_sin,
        q_ws, k_ws, vt);
    attn_mfma_kernel<<<dim3(LL / 64 * BB * HH), 256, 0, stream>>>(
        q_ws, k_ws, vt, ctx);
    gemm_out_kernel<<<dim3(256), 256, 0, stream>>>(
        ctx, Wot, bo, out);
}

// Round 10
// 207.860 us; speedup vs baseline: 1.1050x; 1.0362x over previous
//
#include <hip/hip_runtime.h>
#include <math.h>

// Problem constants (fixed by reference)
#define BB 4
#define LL 1024
#define HH 16
#define DH 64
#define DM 1024
#define MM (BB * LL)   // 4096 rows for the projections

typedef short bf16x8 __attribute__((ext_vector_type(8)));
typedef float f32x4  __attribute__((ext_vector_type(4)));
typedef unsigned short u16x4 __attribute__((ext_vector_type(4)));
typedef unsigned int   u32x2 __attribute__((ext_vector_type(2)));

__device__ __forceinline__ unsigned short f2bf(float x) {
    union { float f; unsigned u; } v; v.f = x;
    unsigned r = v.u + 0x7fff + ((v.u >> 16) & 1);   // round-to-nearest-even
    return (unsigned short)(r >> 16);
}

__device__ __forceinline__ unsigned int fbits(float x) {
    union { float f; unsigned u; } v; v.f = x; return v.u;
}

// async global->LDS, 16B per lane; LDS dest = wave-uniform base + lane*16
__device__ __forceinline__ void gl2lds16(const unsigned short* g, unsigned short* l) {
    __builtin_amdgcn_global_load_lds(
        (const __attribute__((address_space(1))) unsigned int*)g,
        (__attribute__((address_space(3))) unsigned int*)l, 16, 0, 0);
}

// XCD-aware tile mapping for 128x64 tiles (32 M-tiles x 16 N-tiles = 512):
// blocks sharing an A-strip (same tM) have ids congruent mod 8 -> same XCD.
__device__ __forceinline__ void tile_map64(int n, int& tM, int& tN) {
    tM = ((n >> 7) * 8 + (n & 7)) * 128;
    tN = ((n >> 3) & 15) * 64;
}

// ---------------------------------------------------------------------------
// Fused prep kernel, grid (1024, 1, 8):
//  z 0..2 : f32 -> bf16 flat convert of queries/keys/values (16 elem/thread)
//  z == 3 : rope cos/sin table (1024 l x 32 d) — first 128 blocks only
//  z 4..7 : W[K,N] f32 -> Wt[N,K] bf16 transpose, 32x32 tiles (1024 blocks)
// ---------------------------------------------------------------------------
__global__ __launch_bounds__(256) void prep_kernel(
    const float* __restrict__ i0, const float* __restrict__ i1, const float* __restrict__ i2,
    unsigned short* __restrict__ o0, unsigned short* __restrict__ o1, unsigned short* __restrict__ o2,
    const float* __restrict__ w0, const float* __restrict__ w1,
    const float* __restrict__ w2, const float* __restrict__ w3,
    unsigned short* __restrict__ t0, unsigned short* __restrict__ t1,
    unsigned short* __restrict__ t2, unsigned short* __restrict__ t3,
    float* __restrict__ ct, float* __restrict__ st)
{
    const int z = blockIdx.z;
    const int bid = blockIdx.x, tid = threadIdx.x;

    if (z < 3) {
        const float* in = (z == 0) ? i0 : (z == 1) ? i1 : i2;
        unsigned short* out = (z == 0) ? o0 : (z == 1) ? o1 : o2;
        #pragma unroll
        for (int it = 0; it < 4; ++it) {
            size_t i = ((size_t)(it * 1024 + bid) * 256 + tid) * 4;
            float4 f = *(const float4*)(in + i);
            u16x4 r;
            r.x = f2bf(f.x); r.y = f2bf(f.y); r.z = f2bf(f.z); r.w = f2bf(f.w);
            *(u16x4*)(out + i) = r;
        }
    } else if (z == 3) {
        int idx = bid * 256 + tid;
        if (idx < LL * 32) {
            int l = idx >> 5, d = idx & 31;
            const float coef = -0.28782313662425583f;   // -ln(10000)/32
            float ang = (float)l * expf((float)d * coef);
            float s, c;
            sincosf(ang, &s, &c);
            ct[idx] = c;
            st[idx] = s;
        }
    } else {
        const int w = z - 4;
        const float* in = (w == 0) ? w0 : (w == 1) ? w1 : (w == 2) ? w2 : w3;
        unsigned short* out = (w == 0) ? t0 : (w == 1) ? t1 : (w == 2) ? t2 : t3;
        __shared__ float tile[32][33];
        int tx = tid & 31, ty = tid >> 5;   // 32 x 8
        int c0 = (bid & 31) * 32, r0 = (bid >> 5) * 32;
        #pragma unroll
        for (int j = 0; j < 32; j += 8)
            tile[ty + j][tx] = in[(size_t)(r0 + ty + j) * 1024 + c0 + tx];
        __syncthreads();
        #pragma unroll
        for (int j = 0; j < 32; j += 8)
            out[(size_t)(c0 + ty + j) * 1024 + r0 + tx] = f2bf(tile[tx][ty + j]);
    }
}

// ---------------------------------------------------------------------------
// bf16 MFMA GEMM core, 128x64 tile, single-buffered, BK=64, 24 KB LDS
// (-> 6 blocks/CU possible; 128x128 at 32 KB was grid-capped to 3/CU and
//  latency-bound). 4 waves: wm=wave>>1 (2 x 64 rows), wn=wave&1; wave's two
//  n-tiles at cols wn*16 and wn*16+32 (one rope pair per lane).
// LDS unpadded, XOR-swizzled (kb_phys = kb ^ (row&7)).
// ---------------------------------------------------------------------------
__device__ __forceinline__ void gemm128x64_sb(
    const unsigned short* __restrict__ A, const unsigned short* __restrict__ Bt,
    unsigned short* As, unsigned short* Bs, int tM, int tN, f32x4 (&acc)[4][2])
{
    const int tid  = threadIdx.x;
    const int wave = tid >> 6, lane = tid & 63;
    const int g = lane >> 4, lm = lane & 15;
    const int wm = wave >> 1, wn = wave & 1;
    const int lr = lane >> 3, lk = lane & 7;
    const int kbl = lk ^ lr;                    // swizzled k-block for staging

    for (int kt = 0; kt < 16; ++kt) {
        const int k0 = kt * 64;
        if (kt) __syncthreads();
        #pragma unroll
        for (int it = 0; it < 4; ++it) {        // A: 128 rows
            int rbase = wave * 32 + it * 8;
            int r = rbase + lr;
            gl2lds16(A + (size_t)(tM + r) * 1024 + k0 + kbl * 8, As + rbase * 64);
        }
        #pragma unroll
        for (int it = 0; it < 2; ++it) {        // B: 64 rows
            int rbase = wave * 16 + it * 8;
            int r = rbase + lr;
            gl2lds16(Bt + (size_t)(tN + r) * 1024 + k0 + kbl * 8, Bs + rbase * 64);
        }
        __syncthreads();

        #pragma unroll
        for (int kk = 0; kk < 2; ++kk) {
            bf16x8 a[4], b[2];
            const int sw = ((kk * 4 + g) ^ (lm & 7)) * 8;
            #pragma unroll
            for (int mt = 0; mt < 4; ++mt)
                a[mt] = *(const bf16x8*)&As[(wm * 64 + mt * 16 + lm) * 64 + sw];
            #pragma unroll
            for (int nt = 0; nt < 2; ++nt)
                b[nt] = *(const bf16x8*)&Bs[(wn * 16 + nt * 32 + lm) * 64 + sw];
            #pragma unroll
            for (int mt = 0; mt < 4; ++mt)
                #pragma unroll
                for (int nt = 0; nt < 2; ++nt)
                    acc[mt][nt] = __builtin_amdgcn_mfma_f32_16x16x32_bf16(
                        a[mt], b[nt], acc[mt][nt], 0, 0, 0);
        }
    }
}

// ---------------------------------------------------------------------------
// QKV projections, fused over blockIdx.z (0=q rope+scale, 1=k rope, 2=v).
// grid (512, 1, 3) -> 6 blocks/CU. Q scale = 0.125*log2(e) (attn uses exp2).
// Each N-tile (64 cols) = exactly one head. z==2 writes V^T [bh][d][l] (b64).
// ---------------------------------------------------------------------------
__global__ __launch_bounds__(256) void gemm_qkv_kernel(
    const unsigned short* __restrict__ Aq, const unsigned short* __restrict__ Ak,
    const unsigned short* __restrict__ Av,
    const unsigned short* __restrict__ Wqt, const unsigned short* __restrict__ Wkt,
    const unsigned short* __restrict__ Wvt,
    const float* __restrict__ bq, const float* __restrict__ bk, const float* __restrict__ bv,
    const float* __restrict__ ct, const float* __restrict__ st,
    unsigned short* __restrict__ oq, unsigned short* __restrict__ ok,
    unsigned short* __restrict__ vt)
{
    __shared__ __align__(16) unsigned short As[128 * 64];
    __shared__ __align__(16) unsigned short Bs[64 * 64];

    const int z = blockIdx.z;
    const unsigned short* A  = (z == 0) ? Aq  : (z == 1) ? Ak  : Av;
    const unsigned short* Bt = (z == 0) ? Wqt : (z == 1) ? Wkt : Wvt;
    const float* bias        = (z == 0) ? bq  : (z == 1) ? bk  : bv;

    int tM, tN;
    tile_map64(blockIdx.x, tM, tN);
    f32x4 acc[4][2] = {};
    gemm128x64_sb(A, Bt, As, Bs, tM, tN, acc);

    const int wave = threadIdx.x >> 6, lane = threadIdx.x & 63;
    const int g = lane >> 4, lm = lane & 15;
    const int wm = wave >> 1, wn = wave & 1;

    const int h = tN >> 6;                      // this tile's head
    float bvv[2];
    #pragma unroll
    for (int nt = 0; nt < 2; ++nt) bvv[nt] = bias[tN + wn * 16 + nt * 32 + lm];

    if (z == 2) {                               // V: write V^T [bh][d][l], b64
        #pragma unroll
        for (int mt = 0; mt < 4; ++mt) {
            int row0 = tM + wm * 64 + mt * 16 + g * 4;   // 4 consecutive rows
            int b = row0 >> 10, l0 = row0 & 1023;
            #pragma unroll
            for (int nt = 0; nt < 2; ++nt) {
                int dloc = wn * 16 + nt * 32 + lm;
                u16x4 p4;
                #pragma unroll
                for (int r = 0; r < 4; ++r)
                    p4[r] = f2bf(acc[mt][nt][r] + bvv[nt]);
                *(u16x4*)(vt + (((size_t)(b * HH + h) * DH + dloc) << 10) + l0) = p4;
            }
        }
    } else {                                    // Q/K: rope from table
        unsigned short* out = (z == 0) ? oq : ok;
        const float sc = (z == 0) ? 0.125f * 1.4426950408889634f : 1.0f;
        const int dlo = wn * 16 + lm;           // in [0,32): rope pair (dlo, dlo+32)
        #pragma unroll
        for (int mt = 0; mt < 4; ++mt)
            #pragma unroll
            for (int r = 0; r < 4; ++r) {
                int row = tM + wm * 64 + mt * 16 + g * 4 + r;
                int b = row >> 10, l = row & 1023;
                float c = ct[l * 32 + dlo];
                float s = st[l * 32 + dlo];
                unsigned short* orow = out + ((size_t)(b * HH + h) * LL + l) * DH;
                float t1 = acc[mt][0][r] + bvv[0];
                float t2 = acc[mt][1][r] + bvv[1];
                orow[dlo]      = f2bf((t1 * c - t2 * s) * sc);
                orow[dlo + 32] = f2bf((t1 * s + t2 * c) * sc);
            }
    }
}

// ---------------------------------------------------------------------------
// Output projection: f32 C = ctx(bf16).Wot^T + bo. grid (512) -> 2 blocks/CU.
// ---------------------------------------------------------------------------
__global__ __launch_bounds__(256) void gemm_out_kernel(
    const unsigned short* __restrict__ A, const unsigned short* __restrict__ Bt,
    const float* __restrict__ bias, float* __restrict__ C)
{
    __shared__ __align__(16) unsigned short As[128 * 64];
    __shared__ __align__(16) unsigned short Bs[64 * 64];

    int tM, tN;
    tile_map64(blockIdx.x, tM, tN);
    f32x4 acc[4][2] = {};
    gemm128x64_sb(A, Bt, As, Bs, tM, tN, acc);

    const int wave = threadIdx.x >> 6, lane = threadIdx.x & 63;
    const int g = lane >> 4, lm = lane & 15;
    const int wm = wave >> 1, wn = wave & 1;

    float bvv[2];
    #pragma unroll
    for (int nt = 0; nt < 2; ++nt) bvv[nt] = bias[tN + wn * 16 + nt * 32 + lm];
    #pragma unroll
    for (int mt = 0; mt < 4; ++mt)
        #pragma unroll
        for (int r = 0; r < 4; ++r) {
            int row = tM + wm * 64 + mt * 16 + g * 4 + r;
            float* crow = C + (size_t)row * DM + tN;
            #pragma unroll
            for (int nt = 0; nt < 2; ++nt)
                crow[wn * 16 + nt * 32 + lm] = acc[mt][nt][r] + bvv[nt];
        }
}

// ---------------------------------------------------------------------------
// Flash-style bf16 MFMA attention, S^T formulation, single-buffered staging.
// S^T = K.Q^T; MFMA C-layout gives each lane 4 consecutive j for fixed m=lm:
// P packed to LDS [m][j] A-layout with v_perm_b32 TRUNCATION-pack (2 instr
// per 4 elems vs ~14 for RNE; P in [0,1], trunc error <= 0.39% one-sided,
// row sum stays exact f32). Row sums reduced with 2 shuffles at the end.
// 1-D grid, bh = n&63 so each head's 16 blocks share an XCD (L2 locality).
// ---------------------------------------------------------------------------
#define PSTR 72

__global__ __launch_bounds__(256) void attn_mfma_kernel(
    const unsigned short* __restrict__ q, const unsigned short* __restrict__ k,
    const unsigned short* __restrict__ vt, unsigned short* __restrict__ ctx)
{
    __shared__ __align__(16) unsigned short Ks[64 * 64];
    __shared__ __align__(16) unsigned short Vs[64 * 64];
    __shared__ __align__(16) unsigned short Pb[4][16 * PSTR];

    const int tid  = threadIdx.x;
    const int wave = tid >> 6, lane = tid & 63;
    const int g = lane >> 4, lm = lane & 15;
    const int lr = lane >> 3, lk = lane & 7;
    const int kbl = lk ^ lr;
    const int n = blockIdx.x;
    const int bh = n & 63;              // XCD-swizzle: bh%8 == n%8 == XCD
    const int qbase = (n >> 6) * 64;

    const unsigned short* qg  = q  + (size_t)(bh * LL + qbase) * DH;
    const unsigned short* kg  = k  + (size_t)bh * LL * DH;
    const unsigned short* vtg = vt + (size_t)bh * DH * LL;   // [64 d][1024 l]

    bf16x8 aq[2];
    {
        const unsigned short* qrow = qg + (wave * 16 + lm) * DH;
        aq[0] = *(const bf16x8*)(qrow + g * 8);
        aq[1] = *(const bf16x8*)(qrow + 32 + g * 8);
    }

    f32x4 acc[4] = {};
    float lsum = 0.f;                   // row-sum for m = lm (this lane's 16 j)

    for (int kt = 0; kt < 16; ++kt) {
        if (kt) __syncthreads();
        #pragma unroll
        for (int it = 0; it < 2; ++it) {
            int rbase = wave * 16 + it * 8;
            int r = rbase + lr;
            gl2lds16(kg  + (size_t)(kt * 64 + r) * DH + kbl * 8, Ks + rbase * 64);
            gl2lds16(vtg + (size_t)r * LL + kt * 64 + kbl * 8,  Vs + rbase * 64);
        }
        __syncthreads();

        // S^T = K . Q^T : s[t][r] = S[m=lm][j = t*16 + g*4 + r]
        f32x4 s[4] = {};
        #pragma unroll
        for (int kk = 0; kk < 2; ++kk) {
            const int sw = ((kk * 4 + g) ^ (lm & 7)) * 8;
            #pragma unroll
            for (int t = 0; t < 4; ++t) {
                bf16x8 ak = *(const bf16x8*)&Ks[(t * 16 + lm) * 64 + sw];
                s[t] = __builtin_amdgcn_mfma_f32_16x16x32_bf16(ak, aq[kk], s[t], 0, 0, 0);
            }
        }

        // P = exp2(s); truncation-pack via v_perm (bytes [7:6|3:2]); row sum
        #pragma unroll
        for (int t = 0; t < 4; ++t) {
            float p0 = exp2f(s[t][0]), p1 = exp2f(s[t][1]);
            float p2 = exp2f(s[t][2]), p3 = exp2f(s[t][3]);
            lsum += (p0 + p1) + (p2 + p3);
            u32x2 pk;
            pk[0] = __builtin_amdgcn_perm(fbits(p1), fbits(p0), 0x07060302u);
            pk[1] = __builtin_amdgcn_perm(fbits(p3), fbits(p2), 0x07060302u);
            *(u32x2*)&Pb[wave][lm * PSTR + t * 16 + g * 4] = pk;
        }
        // Pb wave-private: same-wave LDS ordering, no barrier needed

        // O += P V
        #pragma unroll
        for (int kk = 0; kk < 2; ++kk) {
            const int sw = ((kk * 4 + g) ^ (lm & 7)) * 8;
            bf16x8 ap = *(const bf16x8*)&Pb[wave][lm * PSTR + kk * 32 + g * 8];
            #pragma unroll
            for (int dt = 0; dt < 4; ++dt) {
                bf16x8 bv = *(const bf16x8*)&Vs[(dt * 16 + lm) * 64 + sw];
                acc[dt] = __builtin_amdgcn_mfma_f32_16x16x32_bf16(ap, bv, acc[dt], 0, 0, 0);
            }
        }
    }

    // Reduce row sums: lanes {lm, lm+16, lm+32, lm+48} hold partials for m=lm
    float ts = lsum;
    ts += __shfl_xor(ts, 16, 64);
    ts += __shfl_xor(ts, 32, 64);

    // Epilogue: lane's C rows are m = g*4+r; fetch their sums via shuffle
    int b = bh >> 4, h = bh & 15;
    #pragma unroll
    for (int r = 0; r < 4; ++r) {
        float inv = 1.f / __shfl(ts, g * 4 + r, 64);
        int qrow = qbase + wave * 16 + g * 4 + r;
        unsigned short* orow = ctx + (size_t)(b * LL + qrow) * DM + h * DH;
        #pragma unroll
        for (int dt = 0; dt < 4; ++dt)
            orow[dt * 16 + lm] = f2bf(acc[dt][r] * inv);
    }
}

// ---------------------------------------------------------------------------
extern "C" void kernel_launch(void* const* d_in, const int* in_sizes, int n_in,
                              void* d_out, int out_size, void* d_ws, size_t ws_size,
                              hipStream_t stream) {
    const float* queries = (const float*)d_in[0];
    const float* keys    = (const float*)d_in[1];
    const float* values  = (const float*)d_in[2];
    const float* Wq = (const float*)d_in[3];
    const float* bq = (const float*)d_in[4];
    const float* Wk = (const float*)d_in[5];
    const float* bk = (const float*)d_in[6];
    const float* Wv = (const float*)d_in[7];
    const float* bv = (const float*)d_in[8];
    const float* Wo = (const float*)d_in[9];
    const float* bo = (const float*)d_in[10];
    float* out = (float*)d_out;

    // Workspace (bf16 elements), 64 MB total. Rope tables (256 KB f32) live at
    // the head of the ctx region: consumed by gemm_qkv BEFORE attn writes ctx.
    unsigned short* qb   = (unsigned short*)d_ws;
    unsigned short* kb_  = qb  + (size_t)MM * DM;
    unsigned short* vb_  = kb_ + (size_t)MM * DM;
    unsigned short* Wqt  = vb_ + (size_t)MM * DM;
    unsigned short* Wkt  = Wqt + (size_t)DM * DM;
    unsigned short* Wvt  = Wkt + (size_t)DM * DM;
    unsigned short* Wot  = Wvt + (size_t)DM * DM;
    unsigned short* q_ws = Wot + (size_t)DM * DM;
    unsigned short* k_ws = q_ws + (size_t)MM * DM;
    unsigned short* vt   = k_ws + (size_t)MM * DM;
    unsigned short* ctx  = vt   + (size_t)MM * DM;
    float* rope_cos = (float*)ctx;                 // 32K floats
    float* rope_sin = rope_cos + LL * 32;          // 32K floats

    prep_kernel<<<dim3(1024, 1, 8), 256, 0, stream>>>(
        queries, keys, values, qb, kb_, vb_,
        Wq, Wk, Wv, Wo, Wqt, Wkt, Wvt, Wot, rope_cos, rope_sin);
    gemm_qkv_kernel<<<dim3(512, 1, 3), 256, 0, stream>>>(
        qb, kb_, vb_, Wqt, Wkt, Wvt, bq, bk, bv, rope_cos, rope_sin,
        q_ws, k_ws, vt);
    attn_mfma_kernel<<<dim3(LL / 64 * BB * HH), 256, 0, stream>>>(
        q_ws, k_ws, vt, ctx);
    gemm_out_kernel<<<dim3(512), 256, 0, stream>>>(
        ctx, Wot, bo, out);
}

// Round 11
// 203.898 us; speedup vs baseline: 1.1265x; 1.0194x over previous
//
#include <hip/hip_runtime.h>
#include <math.h>

// Problem constants (fixed by reference)
#define BB 4
#define LL 1024
#define HH 16
#define DH 64
#define DM 1024
#define MM (BB * LL)   // 4096 rows for the projections

typedef short bf16x8 __attribute__((ext_vector_type(8)));
typedef float f32x4  __attribute__((ext_vector_type(4)));
typedef unsigned short u16x4 __attribute__((ext_vector_type(4)));
typedef unsigned int   u32x2 __attribute__((ext_vector_type(2)));

__device__ __forceinline__ unsigned short f2bf(float x) {
    union { float f; unsigned u; } v; v.f = x;
    unsigned r = v.u + 0x7fff + ((v.u >> 16) & 1);   // round-to-nearest-even
    return (unsigned short)(r >> 16);
}

__device__ __forceinline__ unsigned int fbits(float x) {
    union { float f; unsigned u; } v; v.f = x; return v.u;
}

// async global->LDS, 16B per lane; LDS dest = wave-uniform base + lane*16
__device__ __forceinline__ void gl2lds16(const unsigned short* g, unsigned short* l) {
    __builtin_amdgcn_global_load_lds(
        (const __attribute__((address_space(1))) unsigned int*)g,
        (__attribute__((address_space(3))) unsigned int*)l, 16, 0, 0);
}

// XCD-aware tile mapping for 128x64 tiles (32 M-tiles x 16 N-tiles = 512):
// blocks sharing an A-strip (same tM) have ids congruent mod 8 -> same XCD.
__device__ __forceinline__ void tile_map64(int n, int& tM, int& tN) {
    tM = ((n >> 7) * 8 + (n & 7)) * 128;
    tN = ((n >> 3) & 15) * 64;
}

// ---------------------------------------------------------------------------
// Fused prep kernel, grid (1024, 1, 8):
//  z 0..2 : f32 -> bf16 flat convert of queries/keys/values (16 elem/thread)
//  z == 3 : rope cos/sin table (1024 l x 32 d) — first 128 blocks only
//  z 4..7 : W[K,N] f32 -> Wt[N,K] bf16 transpose, 32x32 tiles (1024 blocks)
// ---------------------------------------------------------------------------
__global__ __launch_bounds__(256) void prep_kernel(
    const float* __restrict__ i0, const float* __restrict__ i1, const float* __restrict__ i2,
    unsigned short* __restrict__ o0, unsigned short* __restrict__ o1, unsigned short* __restrict__ o2,
    const float* __restrict__ w0, const float* __restrict__ w1,
    const float* __restrict__ w2, const float* __restrict__ w3,
    unsigned short* __restrict__ t0, unsigned short* __restrict__ t1,
    unsigned short* __restrict__ t2, unsigned short* __restrict__ t3,
    float* __restrict__ ct, float* __restrict__ st)
{
    const int z = blockIdx.z;
    const int bid = blockIdx.x, tid = threadIdx.x;

    if (z < 3) {
        const float* in = (z == 0) ? i0 : (z == 1) ? i1 : i2;
        unsigned short* out = (z == 0) ? o0 : (z == 1) ? o1 : o2;
        #pragma unroll
        for (int it = 0; it < 4; ++it) {
            size_t i = ((size_t)(it * 1024 + bid) * 256 + tid) * 4;
            float4 f = *(const float4*)(in + i);
            u16x4 r;
            r.x = f2bf(f.x); r.y = f2bf(f.y); r.z = f2bf(f.z); r.w = f2bf(f.w);
            *(u16x4*)(out + i) = r;
        }
    } else if (z == 3) {
        int idx = bid * 256 + tid;
        if (idx < LL * 32) {
            int l = idx >> 5, d = idx & 31;
            const float coef = -0.28782313662425583f;   // -ln(10000)/32
            float ang = (float)l * expf((float)d * coef);
            float s, c;
            sincosf(ang, &s, &c);
            ct[idx] = c;
            st[idx] = s;
        }
    } else {
        const int w = z - 4;
        const float* in = (w == 0) ? w0 : (w == 1) ? w1 : (w == 2) ? w2 : w3;
        unsigned short* out = (w == 0) ? t0 : (w == 1) ? t1 : (w == 2) ? t2 : t3;
        __shared__ float tile[32][33];
        int tx = tid & 31, ty = tid >> 5;   // 32 x 8
        int c0 = (bid & 31) * 32, r0 = (bid >> 5) * 32;
        #pragma unroll
        for (int j = 0; j < 32; j += 8)
            tile[ty + j][tx] = in[(size_t)(r0 + ty + j) * 1024 + c0 + tx];
        __syncthreads();
        #pragma unroll
        for (int j = 0; j < 32; j += 8)
            out[(size_t)(c0 + ty + j) * 1024 + r0 + tx] = f2bf(tile[tx][ty + j]);
    }
}

// ---------------------------------------------------------------------------
// bf16 MFMA GEMM core, 128x64 tile, single-buffered, BK=64, 24 KB LDS.
// LDS unpadded, XOR-swizzled (kb_phys = kb ^ (row&7)); 4 waves, wave's two
// n-tiles at cols wn*16 and wn*16+32 (one rope pair per lane).
// ---------------------------------------------------------------------------
__device__ __forceinline__ void gemm128x64_sb(
    const unsigned short* __restrict__ A, const unsigned short* __restrict__ Bt,
    unsigned short* As, unsigned short* Bs, int tM, int tN, f32x4 (&acc)[4][2])
{
    const int tid  = threadIdx.x;
    const int wave = tid >> 6, lane = tid & 63;
    const int g = lane >> 4, lm = lane & 15;
    const int wm = wave >> 1, wn = wave & 1;
    const int lr = lane >> 3, lk = lane & 7;
    const int kbl = lk ^ lr;                    // swizzled k-block for staging

    for (int kt = 0; kt < 16; ++kt) {
        const int k0 = kt * 64;
        if (kt) __syncthreads();
        #pragma unroll
        for (int it = 0; it < 4; ++it) {        // A: 128 rows
            int rbase = wave * 32 + it * 8;
            int r = rbase + lr;
            gl2lds16(A + (size_t)(tM + r) * 1024 + k0 + kbl * 8, As + rbase * 64);
        }
        #pragma unroll
        for (int it = 0; it < 2; ++it) {        // B: 64 rows
            int rbase = wave * 16 + it * 8;
            int r = rbase + lr;
            gl2lds16(Bt + (size_t)(tN + r) * 1024 + k0 + kbl * 8, Bs + rbase * 64);
        }
        __syncthreads();

        #pragma unroll
        for (int kk = 0; kk < 2; ++kk) {
            bf16x8 a[4], b[2];
            const int sw = ((kk * 4 + g) ^ (lm & 7)) * 8;
            #pragma unroll
            for (int mt = 0; mt < 4; ++mt)
                a[mt] = *(const bf16x8*)&As[(wm * 64 + mt * 16 + lm) * 64 + sw];
            #pragma unroll
            for (int nt = 0; nt < 2; ++nt)
                b[nt] = *(const bf16x8*)&Bs[(wn * 16 + nt * 32 + lm) * 64 + sw];
            #pragma unroll
            for (int mt = 0; mt < 4; ++mt)
                #pragma unroll
                for (int nt = 0; nt < 2; ++nt)
                    acc[mt][nt] = __builtin_amdgcn_mfma_f32_16x16x32_bf16(
                        a[mt], b[nt], acc[mt][nt], 0, 0, 0);
        }
    }
}

// ---------------------------------------------------------------------------
// QKV projections, fused over blockIdx.z (0=q rope+scale, 1=k rope, 2=v).
// grid (512, 1, 3) -> 6 blocks/CU. Q scale = 0.125*log2(e) (attn uses exp2).
// Each N-tile (64 cols) = exactly one head. z==2 writes V^T [bh][d][l] (b64).
// ---------------------------------------------------------------------------
__global__ __launch_bounds__(256) void gemm_qkv_kernel(
    const unsigned short* __restrict__ Aq, const unsigned short* __restrict__ Ak,
    const unsigned short* __restrict__ Av,
    const unsigned short* __restrict__ Wqt, const unsigned short* __restrict__ Wkt,
    const unsigned short* __restrict__ Wvt,
    const float* __restrict__ bq, const float* __restrict__ bk, const float* __restrict__ bv,
    const float* __restrict__ ct, const float* __restrict__ st,
    unsigned short* __restrict__ oq, unsigned short* __restrict__ ok,
    unsigned short* __restrict__ vt)
{
    __shared__ __align__(16) unsigned short As[128 * 64];
    __shared__ __align__(16) unsigned short Bs[64 * 64];

    const int z = blockIdx.z;
    const unsigned short* A  = (z == 0) ? Aq  : (z == 1) ? Ak  : Av;
    const unsigned short* Bt = (z == 0) ? Wqt : (z == 1) ? Wkt : Wvt;
    const float* bias        = (z == 0) ? bq  : (z == 1) ? bk  : bv;

    int tM, tN;
    tile_map64(blockIdx.x, tM, tN);
    f32x4 acc[4][2] = {};
    gemm128x64_sb(A, Bt, As, Bs, tM, tN, acc);

    const int wave = threadIdx.x >> 6, lane = threadIdx.x & 63;
    const int g = lane >> 4, lm = lane & 15;
    const int wm = wave >> 1, wn = wave & 1;

    const int h = tN >> 6;                      // this tile's head
    float bvv[2];
    #pragma unroll
    for (int nt = 0; nt < 2; ++nt) bvv[nt] = bias[tN + wn * 16 + nt * 32 + lm];

    if (z == 2) {                               // V: write V^T [bh][d][l], b64
        #pragma unroll
        for (int mt = 0; mt < 4; ++mt) {
            int row0 = tM + wm * 64 + mt * 16 + g * 4;   // 4 consecutive rows
            int b = row0 >> 10, l0 = row0 & 1023;
            #pragma unroll
            for (int nt = 0; nt < 2; ++nt) {
                int dloc = wn * 16 + nt * 32 + lm;
                u16x4 p4;
                #pragma unroll
                for (int r = 0; r < 4; ++r)
                    p4[r] = f2bf(acc[mt][nt][r] + bvv[nt]);
                *(u16x4*)(vt + (((size_t)(b * HH + h) * DH + dloc) << 10) + l0) = p4;
            }
        }
    } else {                                    // Q/K: rope from table
        unsigned short* out = (z == 0) ? oq : ok;
        const float sc = (z == 0) ? 0.125f * 1.4426950408889634f : 1.0f;
        const int dlo = wn * 16 + lm;           // in [0,32): rope pair (dlo, dlo+32)
        #pragma unroll
        for (int mt = 0; mt < 4; ++mt)
            #pragma unroll
            for (int r = 0; r < 4; ++r) {
                int row = tM + wm * 64 + mt * 16 + g * 4 + r;
                int b = row >> 10, l = row & 1023;
                float c = ct[l * 32 + dlo];
                float s = st[l * 32 + dlo];
                unsigned short* orow = out + ((size_t)(b * HH + h) * LL + l) * DH;
                float t1 = acc[mt][0][r] + bvv[0];
                float t2 = acc[mt][1][r] + bvv[1];
                orow[dlo]      = f2bf((t1 * c - t2 * s) * sc);
                orow[dlo + 32] = f2bf((t1 * s + t2 * c) * sc);
            }
    }
}

// ---------------------------------------------------------------------------
// Output projection: f32 C = ctx(bf16).Wot^T + bo. grid (512) -> 2 blocks/CU.
// ---------------------------------------------------------------------------
__global__ __launch_bounds__(256) void gemm_out_kernel(
    const unsigned short* __restrict__ A, const unsigned short* __restrict__ Bt,
    const float* __restrict__ bias, float* __restrict__ C)
{
    __shared__ __align__(16) unsigned short As[128 * 64];
    __shared__ __align__(16) unsigned short Bs[64 * 64];

    int tM, tN;
    tile_map64(blockIdx.x, tM, tN);
    f32x4 acc[4][2] = {};
    gemm128x64_sb(A, Bt, As, Bs, tM, tN, acc);

    const int wave = threadIdx.x >> 6, lane = threadIdx.x & 63;
    const int g = lane >> 4, lm = lane & 15;
    const int wm = wave >> 1, wn = wave & 1;

    float bvv[2];
    #pragma unroll
    for (int nt = 0; nt < 2; ++nt) bvv[nt] = bias[tN + wn * 16 + nt * 32 + lm];
    #pragma unroll
    for (int mt = 0; mt < 4; ++mt)
        #pragma unroll
        for (int r = 0; r < 4; ++r) {
            int row = tM + wm * 64 + mt * 16 + g * 4 + r;
            float* crow = C + (size_t)row * DM + tN;
            #pragma unroll
            for (int nt = 0; nt < 2; ++nt)
                crow[wn * 16 + nt * 32 + lm] = acc[mt][nt][r] + bvv[nt];
        }
}

// ---------------------------------------------------------------------------
// Flash-style bf16 MFMA attention, S^T form, 512-thread blocks (8 waves).
// Wave pairs: pair = wave>>1 owns q-strip rows pair*16..+15; half = wave&1
// splits the 64 j-columns (QK^T) and 64 d-outputs (PV). Per-wave work per
// tile halves (8 MFMA + 8 exp) while residency doubles: 4 blocks/CU x 8
// waves = 32 waves/CU (LDS 26 KB x 4 = 105 KB). P is pair-shared (disjoint
// j-halves), one barrier before PV. Row sums pair-combined via LDS at end.
// 1-D grid, bh = n&63 so each head's blocks share an XCD (L2 locality).
// ---------------------------------------------------------------------------
#define PSTR 72

__global__ __launch_bounds__(512) void attn_mfma_kernel(
    const unsigned short* __restrict__ q, const unsigned short* __restrict__ k,
    const unsigned short* __restrict__ vt, unsigned short* __restrict__ ctx)
{
    __shared__ __align__(16) unsigned short Ks[64 * 64];
    __shared__ __align__(16) unsigned short Vs[64 * 64];
    __shared__ __align__(16) unsigned short Pb[4][16 * PSTR];
    __shared__ float Sm[4][2][16];

    const int tid  = threadIdx.x;
    const int wave = tid >> 6, lane = tid & 63;
    const int pair = wave >> 1, half = wave & 1;
    const int g = lane >> 4, lm = lane & 15;
    const int lr = lane >> 3, lk = lane & 7;
    const int kbl = lk ^ lr;
    const int n = blockIdx.x;
    const int bh = n & 63;              // XCD-swizzle: bh%8 == n%8 == XCD
    const int qbase = (n >> 6) * 64;

    const unsigned short* qg  = q  + (size_t)(bh * LL + qbase) * DH;
    const unsigned short* kg  = k  + (size_t)bh * LL * DH;
    const unsigned short* vtg = vt + (size_t)bh * DH * LL;   // [64 d][1024 l]

    bf16x8 aq[2];
    {
        const unsigned short* qrow = qg + (pair * 16 + lm) * DH;
        aq[0] = *(const bf16x8*)(qrow + g * 8);
        aq[1] = *(const bf16x8*)(qrow + 32 + g * 8);
    }

    f32x4 acc[2] = {};
    float lsum = 0.f;       // partial row-sum for m=lm over this wave's j-half

    for (int kt = 0; kt < 16; ++kt) {
        if (kt) __syncthreads();
        {   // 8 waves stage 64 K rows + 64 V^T rows in one call each
            int r = wave * 8 + lr;
            gl2lds16(kg  + (size_t)(kt * 64 + r) * DH + kbl * 8, Ks + wave * 8 * 64);
            gl2lds16(vtg + (size_t)r * LL + kt * 64 + kbl * 8,  Vs + wave * 8 * 64);
        }
        __syncthreads();

        // S^T = K . Q^T on this wave's j-half (t-tiles half*2, half*2+1)
        f32x4 s[2] = {};
        #pragma unroll
        for (int kk = 0; kk < 2; ++kk) {
            const int sw = ((kk * 4 + g) ^ (lm & 7)) * 8;
            #pragma unroll
            for (int t = 0; t < 2; ++t) {
                bf16x8 ak = *(const bf16x8*)&Ks[(half * 32 + t * 16 + lm) * 64 + sw];
                s[t] = __builtin_amdgcn_mfma_f32_16x16x32_bf16(ak, aq[kk], s[t], 0, 0, 0);
            }
        }

        // P = exp2(s); truncation-pack via v_perm; partial row sum
        #pragma unroll
        for (int t = 0; t < 2; ++t) {
            float p0 = exp2f(s[t][0]), p1 = exp2f(s[t][1]);
            float p2 = exp2f(s[t][2]), p3 = exp2f(s[t][3]);
            lsum += (p0 + p1) + (p2 + p3);
            u32x2 pk;
            pk[0] = __builtin_amdgcn_perm(fbits(p1), fbits(p0), 0x07060302u);
            pk[1] = __builtin_amdgcn_perm(fbits(p3), fbits(p2), 0x07060302u);
            *(u32x2*)&Pb[pair][lm * PSTR + half * 32 + t * 16 + g * 4] = pk;
        }
        __syncthreads();    // both j-halves of P visible across the pair

        // O += P V on this wave's d-half (dt-tiles half*2, half*2+1)
        #pragma unroll
        for (int kk = 0; kk < 2; ++kk) {
            const int sw = ((kk * 4 + g) ^ (lm & 7)) * 8;
            bf16x8 ap = *(const bf16x8*)&Pb[pair][lm * PSTR + kk * 32 + g * 8];
            #pragma unroll
            for (int dt = 0; dt < 2; ++dt) {
                bf16x8 bv = *(const bf16x8*)&Vs[(half * 32 + dt * 16 + lm) * 64 + sw];
                acc[dt] = __builtin_amdgcn_mfma_f32_16x16x32_bf16(ap, bv, acc[dt], 0, 0, 0);
            }
        }
    }

    // Row sums: reduce over g within wave, then combine halves via LDS
    float ts = lsum;
    ts += __shfl_xor(ts, 16, 64);
    ts += __shfl_xor(ts, 32, 64);
    if (lane < 16) Sm[pair][half][lane] = ts;
    __syncthreads();

    // Epilogue: lane's C rows are m = g*4+r; d = half*32 + dt*16 + lm
    int b = bh >> 4, h = bh & 15;
    #pragma unroll
    for (int r = 0; r < 4; ++r) {
        int m = g * 4 + r;
        float inv = 1.f / (Sm[pair][0][m] + Sm[pair][1][m]);
        int qrow = qbase + pair * 16 + m;
        unsigned short* orow = ctx + (size_t)(b * LL + qrow) * DM + h * DH;
        #pragma unroll
        for (int dt = 0; dt < 2; ++dt)
            orow[half * 32 + dt * 16 + lm] = f2bf(acc[dt][r] * inv);
    }
}

// ---------------------------------------------------------------------------
extern "C" void kernel_launch(void* const* d_in, const int* in_sizes, int n_in,
                              void* d_out, int out_size, void* d_ws, size_t ws_size,
                              hipStream_t stream) {
    const float* queries = (const float*)d_in[0];
    const float* keys    = (const float*)d_in[1];
    const float* values  = (const float*)d_in[2];
    const float* Wq = (const float*)d_in[3];
    const float* bq = (const float*)d_in[4];
    const float* Wk = (const float*)d_in[5];
    const float* bk = (const float*)d_in[6];
    const float* Wv = (const float*)d_in[7];
    const float* bv = (const float*)d_in[8];
    const float* Wo = (const float*)d_in[9];
    const float* bo = (const float*)d_in[10];
    float* out = (float*)d_out;

    // Workspace (bf16 elements), 64 MB total. Rope tables (256 KB f32) live at
    // the head of the ctx region: consumed by gemm_qkv BEFORE attn writes ctx.
    unsigned short* qb   = (unsigned short*)d_ws;
    unsigned short* kb_  = qb  + (size_t)MM * DM;
    unsigned short* vb_  = kb_ + (size_t)MM * DM;
    unsigned short* Wqt  = vb_ + (size_t)MM * DM;
    unsigned short* Wkt  = Wqt + (size_t)DM * DM;
    unsigned short* Wvt  = Wkt + (size_t)DM * DM;
    unsigned short* Wot  = Wvt + (size_t)DM * DM;
    unsigned short* q_ws = Wot + (size_t)DM * DM;
    unsigned short* k_ws = q_ws + (size_t)MM * DM;
    unsigned short* vt   = k_ws + (size_t)MM * DM;
    unsigned short* ctx  = vt   + (size_t)MM * DM;
    float* rope_cos = (float*)ctx;                 // 32K floats
    float* rope_sin = rope_cos + LL * 32;          // 32K floats

    prep_kernel<<<dim3(1024, 1, 8), 256, 0, stream>>>(
        queries, keys, values, qb, kb_, vb_,
        Wq, Wk, Wv, Wo, Wqt, Wkt, Wvt, Wot, rope_cos, rope_sin);
    gemm_qkv_kernel<<<dim3(512, 1, 3), 256, 0, stream>>>(
        qb, kb_, vb_, Wqt, Wkt, Wvt, bq, bk, bv, rope_cos, rope_sin,
        q_ws, k_ws, vt);
    attn_mfma_kernel<<<dim3(LL / 64 * BB * HH), 512, 0, stream>>>(
        q_ws, k_ws, vt, ctx);
    gemm_out_kernel<<<dim3(512), 256, 0, stream>>>(
        ctx, Wot, bo, out);
}